// Round 5
// baseline (3099.785 us; speedup 1.0000x reference)
//
#include <hip/hip_runtime.h>

#define BS   2048     // B*S tokens
#define DM   1024     // D_MODEL
#define RK   256      // RANK
#define NKN  8192     // N_KNOWLEDGE
#define CK   8        // COMPRESS_TOP_K
#define EK   4        // EXPAND_TOP_K
#define KK   8        // KNOWLEDGE_K
#define KCH  32       // knowledge chunks of 256

#define NEGINF -1e30f

// ---------------- LayerNorm: one block per row of 1024 ----------------
__global__ __launch_bounds__(256) void ln_kernel(const float* __restrict__ xin,
    const float* __restrict__ g, const float* __restrict__ bb, float* __restrict__ out) {
  int row = blockIdx.x, t = threadIdx.x;
  __shared__ float red[256];
  const float4 v = *reinterpret_cast<const float4*>(xin + (size_t)row*DM + t*4);
  red[t] = v.x + v.y + v.z + v.w;
  __syncthreads();
  for (int o = 128; o > 0; o >>= 1) { if (t < o) red[t] += red[t+o]; __syncthreads(); }
  float mu = red[0] * (1.f/DM);
  __syncthreads();
  float dx = v.x-mu, dy = v.y-mu, dz = v.z-mu, dw = v.w-mu;
  red[t] = dx*dx + dy*dy + dz*dz + dw*dw;
  __syncthreads();
  for (int o = 128; o > 0; o >>= 1) { if (t < o) red[t] += red[t+o]; __syncthreads(); }
  float rs = rsqrtf(red[0]*(1.f/DM) + 1e-5f);
  float4 gv = *reinterpret_cast<const float4*>(g + t*4);
  float4 bv = *reinterpret_cast<const float4*>(bb + t*4);
  float4 o4 = make_float4(dx*rs*gv.x+bv.x, dy*rs*gv.y+bv.y, dz*rs*gv.z+bv.z, dw*rs*gv.w+bv.w);
  *reinterpret_cast<float4*>(out + (size_t)row*DM + t*4) = o4;
}

// ---- wave-parallel top-k over 64 scores held one-per-lane ----
template<int TOPK>
__device__ inline void wave_topk64(float bv, int lane, float* tops, int* tidx) {
  #pragma unroll
  for (int k = 0; k < TOPK; ++k) {
    float mv = bv; int mp = lane;
    #pragma unroll
    for (int off = 32; off > 0; off >>= 1) {
      float ov = __shfl_xor(mv, off); int op = __shfl_xor(mp, off);
      if (ov > mv || (ov == mv && op < mp)) { mv = ov; mp = op; }
    }
    tops[k] = mv; tidx[k] = mp;
    if (lane == mp) bv = NEGINF;
  }
}

// ------------- Generic router -------------
template<int DIM, int TOPK>
__global__ __launch_bounds__(256) void router_topk(const float* __restrict__ xin,
    const float* __restrict__ rw, float* __restrict__ w_out,
    int* __restrict__ lists, int* __restrict__ counts) {
  int token = blockIdx.x, t = threadIdx.x;
  __shared__ float part[4][64];
  int n = t & 63, c = t >> 6;
  const int CH = DIM / 4;
  const float* xr = xin + (size_t)token*DIM + c*CH;
  const float* wr = rw  + (size_t)n*DIM + c*CH;
  float p = 0.f;
  for (int j = 0; j < CH; j += 4) {
    float4 a = *reinterpret_cast<const float4*>(xr + j);
    float4 b = *reinterpret_cast<const float4*>(wr + j);
    p += a.x*b.x + a.y*b.y + a.z*b.z + a.w*b.w;
  }
  part[c][n] = p;
  __syncthreads();
  if (t < 64) {
    float bv = part[0][t] + part[1][t] + part[2][t] + part[3][t];
    float tops[TOPK]; int tidx[TOPK];
    wave_topk64<TOPK>(bv, t, tops, tidx);
    if (t == 0) {
      float mx = tops[0], se = 0.f, ex[TOPK];
      #pragma unroll
      for (int k = 0; k < TOPK; ++k) { ex[k] = expf(tops[k] - mx); se += ex[k]; }
      float inv = 1.f / se;
      #pragma unroll
      for (int k = 0; k < TOPK; ++k) {
        w_out[token*TOPK + k] = ex[k] * inv;
        int pos = atomicAdd(&counts[tidx[k]], 1);
        lists[tidx[k]*BS + pos] = token*TOPK + k;
      }
    }
  }
}

// ------------- Fused QKV router -------------
__global__ __launch_bounds__(256) void router3(const float* __restrict__ xin,
    const float* __restrict__ w0, const float* __restrict__ w1, const float* __restrict__ w2,
    float* __restrict__ w_all, int* __restrict__ lists, int* __restrict__ counts) {
  int token = blockIdx.x, t = threadIdx.x;
  __shared__ float part[3][4][64];
  int n = t & 63, c = t >> 6;
  const int CH = DM / 4;
  const float* xr = xin + (size_t)token*DM + c*CH;
  const float* a0 = w0 + (size_t)n*DM + c*CH;
  const float* a1 = w1 + (size_t)n*DM + c*CH;
  const float* a2 = w2 + (size_t)n*DM + c*CH;
  float p0 = 0.f, p1 = 0.f, p2 = 0.f;
  for (int j = 0; j < CH; j += 4) {
    float4 a  = *reinterpret_cast<const float4*>(xr + j);
    float4 b0 = *reinterpret_cast<const float4*>(a0 + j);
    float4 b1 = *reinterpret_cast<const float4*>(a1 + j);
    float4 b2 = *reinterpret_cast<const float4*>(a2 + j);
    p0 += a.x*b0.x + a.y*b0.y + a.z*b0.z + a.w*b0.w;
    p1 += a.x*b1.x + a.y*b1.y + a.z*b1.z + a.w*b1.w;
    p2 += a.x*b2.x + a.y*b2.y + a.z*b2.z + a.w*b2.w;
  }
  part[0][c][n] = p0; part[1][c][n] = p1; part[2][c][n] = p2;
  __syncthreads();
  int wv = t >> 6, lane = t & 63;
  if (wv < 3) {
    float bv = part[wv][0][lane] + part[wv][1][lane] + part[wv][2][lane] + part[wv][3][lane];
    float tops[CK]; int tidx[CK];
    wave_topk64<CK>(bv, lane, tops, tidx);
    if (lane == 0) {
      float* wo = w_all + (size_t)wv*BS*CK;
      int* lst  = lists  + (size_t)wv*64*BS;
      int* cnt  = counts + wv*64;
      float mx = tops[0], se = 0.f, ex[CK];
      #pragma unroll
      for (int k = 0; k < CK; ++k) { ex[k] = expf(tops[k] - mx); se += ex[k]; }
      float inv = 1.f / se;
      #pragma unroll
      for (int k = 0; k < CK; ++k) {
        wo[token*CK + k] = ex[k] * inv;
        int pos = atomicAdd(&cnt[tidx[k]], 1);
        lst[tidx[k]*BS + pos] = token*CK + k;
      }
    }
  }
}

// ------------- Grouped expert SGEMM: 64 tok x 256 col, BK=32, 8x8/thread -------------
// Bank-conflict-free column split: thread covers cols {tc*4..+3} and {128+tc*4..+3}.
// Register-staged prefetch hides global latency. grid: (chunk, which*COLCH+cc, expert).
template<int KDIM, int NCOLT, int TK>
__global__ __launch_bounds__(256) void ggemm_f32(const float* __restrict__ xin,
    const float* __restrict__ neurons, const float* __restrict__ w_all,
    const int* __restrict__ lists, const int* __restrict__ counts,
    float* __restrict__ out) {
  constexpr int COLCH = NCOLT / 256;
  int e = blockIdx.z;
  int which = blockIdx.y / COLCH, cc = blockIdx.y % COLCH;
  int cnt = counts[which*64 + e];
  int base = blockIdx.x * 64;
  if (base >= cnt) return;
  const int* list_e = lists + ((size_t)which*64 + e)*BS;
  const float* wvp = w_all + (size_t)which*BS*TK;
  int t = threadIdx.x;
  __shared__ __align__(16) float Bs[32][256];
  __shared__ __align__(16) float At[32][64];
  __shared__ int   toks[64];
  __shared__ float wts[64];
  if (t < 64) {
    int idx = base + t;
    if (idx < cnt) { int e2 = list_e[idx]; toks[t] = e2 / TK; wts[t] = wvp[e2]; }
    else           { toks[t] = -1; wts[t] = 0.f; }
  }
  __syncthreads();
  float acc[8][8];
  #pragma unroll
  for (int i = 0; i < 8; ++i)
    #pragma unroll
    for (int j = 0; j < 8; ++j) acc[i][j] = 0.f;
  int tr = t >> 5, tc = t & 31;
  const float* W = neurons + (size_t)e*KDIM*NCOLT + cc*256;

  float4 bReg[8], aReg[2];
  auto loadB = [&](int k0) {
    #pragma unroll
    for (int it = 0; it < 8; ++it) {
      int f = it*1024 + t*4;
      bReg[it] = *reinterpret_cast<const float4*>(W + (size_t)(k0 + (f>>8))*NCOLT + (f&255));
    }
  };
  auto loadA = [&](int k0) {
    #pragma unroll
    for (int it = 0; it < 2; ++it) {
      int l = t + it*256;
      int r = l & 63, kc = (l >> 6) * 4;
      int tok = toks[r];
      aReg[it] = (tok >= 0)
          ? *reinterpret_cast<const float4*>(xin + (size_t)tok*KDIM + k0 + kc)
          : make_float4(0.f, 0.f, 0.f, 0.f);
    }
  };
  loadB(0); loadA(0);
  for (int k0 = 0; k0 < KDIM; k0 += 32) {
    __syncthreads();   // previous compute done reading LDS
    #pragma unroll
    for (int it = 0; it < 8; ++it) {
      int f = it*1024 + t*4;
      *reinterpret_cast<float4*>(&Bs[f>>8][f&255]) = bReg[it];
    }
    #pragma unroll
    for (int it = 0; it < 2; ++it) {
      int l = t + it*256;
      int r = l & 63, kc = (l >> 6) * 4;
      At[kc+0][r] = aReg[it].x; At[kc+1][r] = aReg[it].y;
      At[kc+2][r] = aReg[it].z; At[kc+3][r] = aReg[it].w;
    }
    __syncthreads();
    if (k0 + 32 < KDIM) { loadB(k0 + 32); loadA(k0 + 32); }
    #pragma unroll 4
    for (int kk = 0; kk < 32; ++kk) {
      float4 a0 = *reinterpret_cast<const float4*>(&At[kk][tr*8]);
      float4 a1 = *reinterpret_cast<const float4*>(&At[kk][tr*8 + 4]);
      float4 b0 = *reinterpret_cast<const float4*>(&Bs[kk][tc*4]);
      float4 b1 = *reinterpret_cast<const float4*>(&Bs[kk][128 + tc*4]);
      float a[8] = {a0.x,a0.y,a0.z,a0.w,a1.x,a1.y,a1.z,a1.w};
      float b[8] = {b0.x,b0.y,b0.z,b0.w,b1.x,b1.y,b1.z,b1.w};
      #pragma unroll
      for (int i = 0; i < 8; ++i)
        #pragma unroll
        for (int j = 0; j < 8; ++j)
          acc[i][j] = fmaf(a[i], b[j], acc[i][j]);
    }
  }
  #pragma unroll
  for (int i = 0; i < 8; ++i) {
    int r = tr*8 + i;
    int tok = toks[r];
    if (tok < 0) continue;
    float wt = wts[r];
    float* orow = out + ((size_t)which*BS + tok)*NCOLT + cc*256;
    #pragma unroll
    for (int j = 0; j < 4; ++j) {
      atomicAdd(&orow[tc*4 + j],       wt * acc[i][j]);
      atomicAdd(&orow[128 + tc*4 + j], wt * acc[i][j+4]);
    }
  }
}

// ------------- Attention: one block per (q, head*batch) -------------
__global__ __launch_bounds__(256) void attn_kernel(const float* __restrict__ Q,
    const float* __restrict__ K, const float* __restrict__ V, float* __restrict__ AO) {
  int qs = blockIdx.x;
  int hb = blockIdx.y; int h = hb & 7, b = hb >> 3;
  int t = threadIdx.x;
  __shared__ float qv[32];
  __shared__ float sc[512];
  __shared__ float red[256];
  const size_t baseQ = ((size_t)(b*512 + qs))*RK + h*32;
  if (t < 32) qv[t] = Q[baseQ + t];
  __syncthreads();
  int nk = qs + 1;
  const float scale = 0.17677669529663687f;  // 1/sqrt(32)
  for (int k = t; k < nk; k += 256) {
    const float* kr = K + ((size_t)(b*512 + k))*RK + h*32;
    float s = 0.f;
    #pragma unroll
    for (int d = 0; d < 32; d += 4) {
      float4 kv = *reinterpret_cast<const float4*>(kr + d);
      s += kv.x*qv[d] + kv.y*qv[d+1] + kv.z*qv[d+2] + kv.w*qv[d+3];
    }
    sc[k] = s * scale;
  }
  __syncthreads();
  float m = NEGINF;
  for (int k = t; k < nk; k += 256) m = fmaxf(m, sc[k]);
  red[t] = m; __syncthreads();
  for (int o = 128; o > 0; o >>= 1) { if (t < o) red[t] = fmaxf(red[t], red[t+o]); __syncthreads(); }
  m = red[0];
  __syncthreads();
  float sloc = 0.f;
  for (int k = t; k < nk; k += 256) { float pp = expf(sc[k] - m); sc[k] = pp; sloc += pp; }
  red[t] = sloc; __syncthreads();
  for (int o = 128; o > 0; o >>= 1) { if (t < o) red[t] += red[t+o]; __syncthreads(); }
  float inv = 1.f / red[0];
  __syncthreads();
  int d = t & 31, c = t >> 5;
  float pa = 0.f;
  for (int k = c; k < nk; k += 8)
    pa += sc[k] * V[((size_t)(b*512 + k))*RK + h*32 + d];
  red[c*32 + d] = pa; __syncthreads();
  if (t < 32) {
    float o = 0.f;
    #pragma unroll
    for (int c2 = 0; c2 < 8; ++c2) o += red[c2*32 + t];
    AO[baseQ + t] = o * inv;
  }
}

// ------------- Transpose knowledge_K [8192][256] -> KT [256][8192] -------------
__global__ __launch_bounds__(256) void transpose_k(const float* __restrict__ kK,
                                                   float* __restrict__ KT) {
  __shared__ float tile[32][33];
  int bx = blockIdx.x, by = blockIdx.y;
  int tx = threadIdx.x & 31, ty = threadIdx.x >> 5;
  for (int r = ty; r < 32; r += 8)
    tile[r][tx] = kK[(size_t)(bx*32 + r)*RK + by*32 + tx];
  __syncthreads();
  for (int r = ty; r < 32; r += 8)
    KT[(size_t)(by*32 + r)*NKN + bx*32 + tx] = tile[tx][r];
}

// ------------- Knowledge scores: SGEMM 64 tok x 256 entries + per-chunk top-8 -------------
// grid: (32 token-tiles of 64, 32 chunks)
__global__ __launch_bounds__(256) void kscore(const float* __restrict__ Qm,
    const float* __restrict__ KT, float* __restrict__ cand_s, int* __restrict__ cand_i) {
  int tile = blockIdx.x, chunk = blockIdx.y, t = threadIdx.x;
  __shared__ __align__(16) char smem[64*258*4];  // 66048 B arena
  float (*Bs)[256] = reinterpret_cast<float(*)[256]>(smem);
  float (*At)[64]  = reinterpret_cast<float(*)[64]>(smem + 32*256*4);
  float (*sc)[258] = reinterpret_cast<float(*)[258]>(smem);
  float acc[8][8];
  #pragma unroll
  for (int i = 0; i < 8; ++i)
    #pragma unroll
    for (int j = 0; j < 8; ++j) acc[i][j] = 0.f;
  int tr = t >> 5, tc = t & 31;
  float4 bReg[8], aReg[2];
  auto loadB = [&](int k0) {
    #pragma unroll
    for (int it = 0; it < 8; ++it) {
      int f = it*1024 + t*4;
      bReg[it] = *reinterpret_cast<const float4*>(KT + (size_t)(k0 + (f>>8))*NKN + chunk*256 + (f&255));
    }
  };
  auto loadA = [&](int k0) {
    #pragma unroll
    for (int it = 0; it < 2; ++it) {
      int l = t + it*256;
      int r = l & 63, kc = (l >> 6) * 4;
      aReg[it] = *reinterpret_cast<const float4*>(Qm + (size_t)(tile*64 + r)*RK + k0 + kc);
    }
  };
  loadB(0); loadA(0);
  for (int k0 = 0; k0 < RK; k0 += 32) {
    __syncthreads();
    #pragma unroll
    for (int it = 0; it < 8; ++it) {
      int f = it*1024 + t*4;
      *reinterpret_cast<float4*>(&Bs[f>>8][f&255]) = bReg[it];
    }
    #pragma unroll
    for (int it = 0; it < 2; ++it) {
      int l = t + it*256;
      int r = l & 63, kc = (l >> 6) * 4;
      At[kc+0][r] = aReg[it].x; At[kc+1][r] = aReg[it].y;
      At[kc+2][r] = aReg[it].z; At[kc+3][r] = aReg[it].w;
    }
    __syncthreads();
    if (k0 + 32 < RK) { loadB(k0 + 32); loadA(k0 + 32); }
    #pragma unroll 4
    for (int kk = 0; kk < 32; ++kk) {
      float4 a0 = *reinterpret_cast<const float4*>(&At[kk][tr*8]);
      float4 a1 = *reinterpret_cast<const float4*>(&At[kk][tr*8 + 4]);
      float4 b0 = *reinterpret_cast<const float4*>(&Bs[kk][tc*4]);
      float4 b1 = *reinterpret_cast<const float4*>(&Bs[kk][128 + tc*4]);
      float a[8] = {a0.x,a0.y,a0.z,a0.w,a1.x,a1.y,a1.z,a1.w};
      float b[8] = {b0.x,b0.y,b0.z,b0.w,b1.x,b1.y,b1.z,b1.w};
      #pragma unroll
      for (int i = 0; i < 8; ++i)
        #pragma unroll
        for (int j = 0; j < 8; ++j)
          acc[i][j] = fmaf(a[i], b[j], acc[i][j]);
    }
  }
  __syncthreads();  // done with Bs/At; reuse arena for scores
  #pragma unroll
  for (int i = 0; i < 8; ++i)
    #pragma unroll
    for (int j = 0; j < 4; ++j) {
      sc[tr*8 + i][tc*4 + j]       = acc[i][j];
      sc[tr*8 + i][128 + tc*4 + j] = acc[i][j+4];
    }
  __syncthreads();
  // per-token top-8 over this chunk's 256 entries
  int lane = t & 63, wv = t >> 6;
  for (int s = 0; s < 16; ++s) {
    int tok = wv*16 + s;
    float v0 = sc[tok][lane], v1 = sc[tok][lane+64], v2 = sc[tok][lane+128], v3 = sc[tok][lane+192];
    size_t cbase = ((size_t)(tile*64 + tok)*KCH + chunk)*KK;
    #pragma unroll
    for (int iter = 0; iter < KK; ++iter) {
      float mv = v0; int mp = lane;
      if (v1 > mv) { mv = v1; mp = lane+64; }
      if (v2 > mv) { mv = v2; mp = lane+128; }
      if (v3 > mv) { mv = v3; mp = lane+192; }
      #pragma unroll
      for (int off = 32; off > 0; off >>= 1) {
        float ov = __shfl_xor(mv, off); int op = __shfl_xor(mp, off);
        if (ov > mv || (ov == mv && op < mp)) { mv = ov; mp = op; }
      }
      if ((mp & 63) == lane) {
        int j = mp >> 6;
        if (j == 0) v0 = NEGINF; else if (j == 1) v1 = NEGINF;
        else if (j == 2) v2 = NEGINF; else v3 = NEGINF;
      }
      if (lane == 0) { cand_s[cbase + iter] = mv; cand_i[cbase + iter] = chunk*256 + mp; }
    }
  }
}

// ------------- Knowledge merge: 256 candidates -> top-8, softmax, V gather -------------
__global__ __launch_bounds__(256) void knowledge_merge(const float* __restrict__ cand_s,
    const int* __restrict__ cand_i, const float* __restrict__ kV, float* __restrict__ xout) {
  int tok = blockIdx.x, t = threadIdx.x;
  __shared__ float s_sc[256];
  __shared__ int   s_ix[256];
  __shared__ float w8[KK];
  __shared__ int   i8[KK];
  s_sc[t] = cand_s[(size_t)tok*256 + t];
  s_ix[t] = cand_i[(size_t)tok*256 + t];
  __syncthreads();
  if (t < 64) {
    float v0 = s_sc[t], v1 = s_sc[t+64], v2 = s_sc[t+128], v3 = s_sc[t+192];
    float tops[KK]; int tpos[KK];
    #pragma unroll
    for (int iter = 0; iter < KK; ++iter) {
      float mv = v0; int mp = t;
      if (v1 > mv) { mv = v1; mp = t+64; }
      if (v2 > mv) { mv = v2; mp = t+128; }
      if (v3 > mv) { mv = v3; mp = t+192; }
      #pragma unroll
      for (int off = 32; off > 0; off >>= 1) {
        float ov = __shfl_xor(mv, off); int op = __shfl_xor(mp, off);
        if (ov > mv || (ov == mv && op < mp)) { mv = ov; mp = op; }
      }
      tops[iter] = mv; tpos[iter] = mp;
      if ((mp & 63) == t) {
        int j = mp >> 6;
        if (j == 0) v0 = NEGINF; else if (j == 1) v1 = NEGINF;
        else if (j == 2) v2 = NEGINF; else v3 = NEGINF;
      }
    }
    if (t == 0) {
      const float kscale = 1.f/16.f;  // 1/sqrt(256)
      float mx = tops[0]*kscale, se = 0.f, ex[KK];
      #pragma unroll
      for (int k = 0; k < KK; ++k) { ex[k] = expf(tops[k]*kscale - mx); se += ex[k]; }
      float inv = 1.f / se;
      #pragma unroll
      for (int k = 0; k < KK; ++k) { w8[k] = ex[k]*inv; i8[k] = s_ix[tpos[k]]; }
    }
  }
  __syncthreads();
  size_t orow = (size_t)tok * DM;
  float4 o = *reinterpret_cast<const float4*>(xout + orow + t*4);
  #pragma unroll
  for (int k = 0; k < KK; ++k) {
    float w = w8[k];
    const float4 v4 = *reinterpret_cast<const float4*>(kV + (size_t)i8[k]*DM + t*4);
    o.x += w*v4.x; o.y += w*v4.y; o.z += w*v4.z; o.w += w*v4.w;
  }
  *reinterpret_cast<float4*>(xout + orow + t*4) = o;
}

extern "C" void kernel_launch(void* const* d_in, const int* in_sizes, int n_in,
                              void* d_out, int out_size, void* d_ws, size_t ws_size,
                              hipStream_t stream) {
  const float* x  = (const float*)d_in[0];
  const float* cn = (const float*)d_in[2];
  const float* en = (const float*)d_in[3];
  const float* kK = (const float*)d_in[4];
  const float* kV = (const float*)d_in[5];
  const float* rq = (const float*)d_in[6];
  const float* rk = (const float*)d_in[7];
  const float* rv = (const float*)d_in[8];
  const float* ro = (const float*)d_in[9];
  const float* rm = (const float*)d_in[10];
  const float* g1 = (const float*)d_in[11];
  const float* b1 = (const float*)d_in[12];
  const float* g2 = (const float*)d_in[13];
  const float* b2 = (const float*)d_in[14];
  float* out = (float*)d_out;

  char* p = (char*)d_ws;
  auto alloc = [&](size_t bytes) { char* r = p; p += (bytes + 255) & ~(size_t)255; return r; };
  float* h    = (float*)alloc((size_t)BS*DM*4);
  float* h2   = (float*)alloc((size_t)BS*DM*4);
  float* KT   = (float*)alloc((size_t)RK*NKN*4);
  float* Q    = (float*)alloc((size_t)BS*RK*4);   // Q,Kb,Vb,Qm contiguous for one memset
  float* Kb   = (float*)alloc((size_t)BS*RK*4);
  float* Vb   = (float*)alloc((size_t)BS*RK*4);
  float* Qm   = (float*)alloc((size_t)BS*RK*4);
  float* AO   = (float*)alloc((size_t)BS*RK*4);
  float* w_all= (float*)alloc((size_t)3*BS*CK*4);
  float* w_o  = (float*)alloc((size_t)BS*EK*4);
  float* w_m  = (float*)alloc((size_t)BS*CK*4);
  float* cand_s = (float*)alloc((size_t)BS*KCH*KK*4);
  int*   cand_i = (int*)  alloc((size_t)BS*KCH*KK*4);
  int* lists  = (int*)alloc((size_t)5*64*BS*4);   // [q,k,v,o,m]
  int* counts = (int*)alloc((size_t)5*64*4);

  int *listo = lists + 3*64*BS, *listm = lists + 4*64*BS;
  int *co = counts + 192, *cm = counts + 256;

  hipMemsetAsync(counts, 0, 5*64*4, stream);
  hipMemsetAsync(Q, 0, (size_t)BS*RK*4*4, stream);  // zeros Q, Kb, Vb, Qm

  ln_kernel<<<BS, 256, 0, stream>>>(x, g1, b1, h);

  router3<<<BS, 256, 0, stream>>>(h, rq, rk, rv, w_all, lists, counts);
  ggemm_f32<DM, RK, CK><<<dim3(16, 3, 64), 256, 0, stream>>>(h, cn, w_all, lists, counts, Q);

  attn_kernel<<<dim3(512, 32), 256, 0, stream>>>(Q, Kb, Vb, AO);

  hipMemcpyAsync(out, x, (size_t)BS*DM*4, hipMemcpyDeviceToDevice, stream);  // out = x

  router_topk<RK, EK><<<BS, 256, 0, stream>>>(AO, ro, w_o, listo, co);
  ggemm_f32<RK, DM, EK><<<dim3(16, 4, 64), 256, 0, stream>>>(AO, en, w_o, listo, co, out); // out = x1

  ln_kernel<<<BS, 256, 0, stream>>>(out, g2, b2, h2);
  router_topk<DM, CK><<<BS, 256, 0, stream>>>(h2, rm, w_m, listm, cm);
  ggemm_f32<DM, RK, CK><<<dim3(16, 1, 64), 256, 0, stream>>>(h2, cn, w_m, listm, cm, Qm);

  transpose_k<<<dim3(NKN/32, RK/32), 256, 0, stream>>>(kK, KT);
  kscore<<<dim3(BS/64, KCH), 256, 0, stream>>>(Qm, KT, cand_s, cand_i);
  knowledge_merge<<<BS, 256, 0, stream>>>(cand_s, cand_i, kV, out);  // out = x1 + mem_out
}

// Round 6
// 2639.525 us; speedup vs baseline: 1.1744x; 1.1744x over previous
//
#include <hip/hip_runtime.h>

#define BS   2048     // B*S tokens
#define DM   1024     // D_MODEL
#define RK   256      // RANK
#define NKN  8192     // N_KNOWLEDGE
#define CK   8        // COMPRESS_TOP_K
#define EK   4        // EXPAND_TOP_K
#define KK   8        // KNOWLEDGE_K
#define KCH  32       // knowledge chunks of 256

#define NEGINF -1e30f

// HBM -> LDS direct DMA, 16 bytes per lane. LDS dest must be uniform_base + lane*16.
__device__ __forceinline__ void gl_lds16(const float* g, float* l) {
  __builtin_amdgcn_global_load_lds(
      (const __attribute__((address_space(1))) void*)g,
      (__attribute__((address_space(3))) void*)l, 16, 0, 0);
}

// ---------------- LayerNorm: one block per row of 1024 ----------------
__global__ __launch_bounds__(256) void ln_kernel(const float* __restrict__ xin,
    const float* __restrict__ g, const float* __restrict__ bb, float* __restrict__ out) {
  int row = blockIdx.x, t = threadIdx.x;
  __shared__ float red[256];
  const float4 v = *reinterpret_cast<const float4*>(xin + (size_t)row*DM + t*4);
  red[t] = v.x + v.y + v.z + v.w;
  __syncthreads();
  for (int o = 128; o > 0; o >>= 1) { if (t < o) red[t] += red[t+o]; __syncthreads(); }
  float mu = red[0] * (1.f/DM);
  __syncthreads();
  float dx = v.x-mu, dy = v.y-mu, dz = v.z-mu, dw = v.w-mu;
  red[t] = dx*dx + dy*dy + dz*dz + dw*dw;
  __syncthreads();
  for (int o = 128; o > 0; o >>= 1) { if (t < o) red[t] += red[t+o]; __syncthreads(); }
  float rs = rsqrtf(red[0]*(1.f/DM) + 1e-5f);
  float4 gv = *reinterpret_cast<const float4*>(g + t*4);
  float4 bv = *reinterpret_cast<const float4*>(bb + t*4);
  float4 o4 = make_float4(dx*rs*gv.x+bv.x, dy*rs*gv.y+bv.y, dz*rs*gv.z+bv.z, dw*rs*gv.w+bv.w);
  *reinterpret_cast<float4*>(out + (size_t)row*DM + t*4) = o4;
}

// ---- wave-parallel top-k over 64 scores held one-per-lane ----
template<int TOPK>
__device__ inline void wave_topk64(float bv, int lane, float* tops, int* tidx) {
  #pragma unroll
  for (int k = 0; k < TOPK; ++k) {
    float mv = bv; int mp = lane;
    #pragma unroll
    for (int off = 32; off > 0; off >>= 1) {
      float ov = __shfl_xor(mv, off); int op = __shfl_xor(mp, off);
      if (ov > mv || (ov == mv && op < mp)) { mv = ov; mp = op; }
    }
    tops[k] = mv; tidx[k] = mp;
    if (lane == mp) bv = NEGINF;
  }
}

// ------------- Generic router -------------
template<int DIM, int TOPK>
__global__ __launch_bounds__(256) void router_topk(const float* __restrict__ xin,
    const float* __restrict__ rw, float* __restrict__ w_out,
    int* __restrict__ lists, int* __restrict__ counts) {
  int token = blockIdx.x, t = threadIdx.x;
  __shared__ float part[4][64];
  int n = t & 63, c = t >> 6;
  const int CH = DIM / 4;
  const float* xr = xin + (size_t)token*DIM + c*CH;
  const float* wr = rw  + (size_t)n*DIM + c*CH;
  float p = 0.f;
  for (int j = 0; j < CH; j += 4) {
    float4 a = *reinterpret_cast<const float4*>(xr + j);
    float4 b = *reinterpret_cast<const float4*>(wr + j);
    p += a.x*b.x + a.y*b.y + a.z*b.z + a.w*b.w;
  }
  part[c][n] = p;
  __syncthreads();
  if (t < 64) {
    float bv = part[0][t] + part[1][t] + part[2][t] + part[3][t];
    float tops[TOPK]; int tidx[TOPK];
    wave_topk64<TOPK>(bv, t, tops, tidx);
    if (t == 0) {
      float mx = tops[0], se = 0.f, ex[TOPK];
      #pragma unroll
      for (int k = 0; k < TOPK; ++k) { ex[k] = expf(tops[k] - mx); se += ex[k]; }
      float inv = 1.f / se;
      #pragma unroll
      for (int k = 0; k < TOPK; ++k) {
        w_out[token*TOPK + k] = ex[k] * inv;
        int pos = atomicAdd(&counts[tidx[k]], 1);
        lists[tidx[k]*BS + pos] = token*TOPK + k;
      }
    }
  }
}

// ------------- Fused QKV router -------------
__global__ __launch_bounds__(256) void router3(const float* __restrict__ xin,
    const float* __restrict__ w0, const float* __restrict__ w1, const float* __restrict__ w2,
    float* __restrict__ w_all, int* __restrict__ lists, int* __restrict__ counts) {
  int token = blockIdx.x, t = threadIdx.x;
  __shared__ float part[3][4][64];
  int n = t & 63, c = t >> 6;
  const int CH = DM / 4;
  const float* xr = xin + (size_t)token*DM + c*CH;
  const float* a0 = w0 + (size_t)n*DM + c*CH;
  const float* a1 = w1 + (size_t)n*DM + c*CH;
  const float* a2 = w2 + (size_t)n*DM + c*CH;
  float p0 = 0.f, p1 = 0.f, p2 = 0.f;
  for (int j = 0; j < CH; j += 4) {
    float4 a  = *reinterpret_cast<const float4*>(xr + j);
    float4 b0 = *reinterpret_cast<const float4*>(a0 + j);
    float4 b1 = *reinterpret_cast<const float4*>(a1 + j);
    float4 b2 = *reinterpret_cast<const float4*>(a2 + j);
    p0 += a.x*b0.x + a.y*b0.y + a.z*b0.z + a.w*b0.w;
    p1 += a.x*b1.x + a.y*b1.y + a.z*b1.z + a.w*b1.w;
    p2 += a.x*b2.x + a.y*b2.y + a.z*b2.z + a.w*b2.w;
  }
  part[0][c][n] = p0; part[1][c][n] = p1; part[2][c][n] = p2;
  __syncthreads();
  int wv = t >> 6, lane = t & 63;
  if (wv < 3) {
    float bv = part[wv][0][lane] + part[wv][1][lane] + part[wv][2][lane] + part[wv][3][lane];
    float tops[CK]; int tidx[CK];
    wave_topk64<CK>(bv, lane, tops, tidx);
    if (lane == 0) {
      float* wo = w_all + (size_t)wv*BS*CK;
      int* lst  = lists  + (size_t)wv*64*BS;
      int* cnt  = counts + wv*64;
      float mx = tops[0], se = 0.f, ex[CK];
      #pragma unroll
      for (int k = 0; k < CK; ++k) { ex[k] = expf(tops[k] - mx); se += ex[k]; }
      float inv = 1.f / se;
      #pragma unroll
      for (int k = 0; k < CK; ++k) {
        wo[token*CK + k] = ex[k] * inv;
        int pos = atomicAdd(&cnt[tidx[k]], 1);
        lst[tidx[k]*BS + pos] = token*CK + k;
      }
    }
  }
}

// ------------- Grouped expert SGEMM: 64 tok x 256 col, BK=32, 8x8/thread -------------
// B staged via global_load_lds DMA (no VGPR round-trip); A via float4->4 ds_writes.
// Conflict-free column split: cols {tc*4..+3} and {128+tc*4..+3}.
// grid: (token_chunk, which*COLCH+cc, expert)
template<int KDIM, int NCOLT, int TK>
__global__ __launch_bounds__(256) void ggemm_f32(const float* __restrict__ xin,
    const float* __restrict__ neurons, const float* __restrict__ w_all,
    const int* __restrict__ lists, const int* __restrict__ counts,
    float* __restrict__ out) {
  constexpr int COLCH = NCOLT / 256;
  int e = blockIdx.z;
  int which = blockIdx.y / COLCH, cc = blockIdx.y % COLCH;
  int cnt = counts[which*64 + e];
  int base = blockIdx.x * 64;
  if (base >= cnt) return;
  const int* list_e = lists + ((size_t)which*64 + e)*BS;
  const float* wvp = w_all + (size_t)which*BS*TK;
  int t = threadIdx.x;
  __shared__ __align__(16) float Bs[32][256];
  __shared__ __align__(16) float At[32][64];
  __shared__ int   toks[64];
  __shared__ float wts[64];
  if (t < 64) {
    int idx = base + t;
    if (idx < cnt) { int e2 = list_e[idx]; toks[t] = e2 / TK; wts[t] = wvp[e2]; }
    else           { toks[t] = -1; wts[t] = 0.f; }
  }
  __syncthreads();
  float acc[8][8];
  #pragma unroll
  for (int i = 0; i < 8; ++i)
    #pragma unroll
    for (int j = 0; j < 8; ++j) acc[i][j] = 0.f;
  int tr = t >> 5, tc = t & 31;
  const float* W = neurons + (size_t)e*KDIM*NCOLT + cc*256;
  // A-staging indices (fixed per thread)
  int ar0 = t & 63,        akc0 = (t >> 6) * 4;
  int ar1 = (t+256) & 63,  akc1 = ((t+256) >> 6) * 4;
  int tokA0 = toks[ar0], tokA1 = toks[ar1];
  for (int k0 = 0; k0 < KDIM; k0 += 32) {
    // B tile [32 k][256 col]: direct HBM->LDS DMA, 8 x 16B per thread (linear)
    #pragma unroll
    for (int it = 0; it < 8; ++it) {
      int f = it*1024 + t*4;                 // dword index in tile
      gl_lds16(W + (size_t)(k0 + (f >> 8))*NCOLT + (f & 255), &Bs[0][0] + f);
    }
    // A tile transposed [32 k][64 tok]
    {
      float4 v0 = (tokA0 >= 0)
          ? *reinterpret_cast<const float4*>(xin + (size_t)tokA0*KDIM + k0 + akc0)
          : make_float4(0.f,0.f,0.f,0.f);
      float4 v1 = (tokA1 >= 0)
          ? *reinterpret_cast<const float4*>(xin + (size_t)tokA1*KDIM + k0 + akc1)
          : make_float4(0.f,0.f,0.f,0.f);
      At[akc0+0][ar0] = v0.x; At[akc0+1][ar0] = v0.y; At[akc0+2][ar0] = v0.z; At[akc0+3][ar0] = v0.w;
      At[akc1+0][ar1] = v1.x; At[akc1+1][ar1] = v1.y; At[akc1+2][ar1] = v1.z; At[akc1+3][ar1] = v1.w;
    }
    __syncthreads();   // drains DMA (vmcnt) + LDS writes
    #pragma unroll 4
    for (int kk = 0; kk < 32; ++kk) {
      float4 a0 = *reinterpret_cast<const float4*>(&At[kk][tr*8]);
      float4 a1 = *reinterpret_cast<const float4*>(&At[kk][tr*8 + 4]);
      float4 b0 = *reinterpret_cast<const float4*>(&Bs[kk][tc*4]);
      float4 b1 = *reinterpret_cast<const float4*>(&Bs[kk][128 + tc*4]);
      float a[8] = {a0.x,a0.y,a0.z,a0.w,a1.x,a1.y,a1.z,a1.w};
      float b[8] = {b0.x,b0.y,b0.z,b0.w,b1.x,b1.y,b1.z,b1.w};
      #pragma unroll
      for (int i = 0; i < 8; ++i)
        #pragma unroll
        for (int j = 0; j < 8; ++j)
          acc[i][j] = fmaf(a[i], b[j], acc[i][j]);
    }
    __syncthreads();   // compute done before next stage overwrites LDS
  }
  #pragma unroll
  for (int i = 0; i < 8; ++i) {
    int r = tr*8 + i;
    int tok = toks[r];
    if (tok < 0) continue;
    float wt = wts[r];
    float* orow = out + ((size_t)which*BS + tok)*NCOLT + cc*256;
    #pragma unroll
    for (int j = 0; j < 4; ++j) {
      atomicAdd(&orow[tc*4 + j],       wt * acc[i][j]);
      atomicAdd(&orow[128 + tc*4 + j], wt * acc[i][j+4]);
    }
  }
}

// ------------- Attention: one block per (q, head*batch) -------------
__global__ __launch_bounds__(256) void attn_kernel(const float* __restrict__ Q,
    const float* __restrict__ K, const float* __restrict__ V, float* __restrict__ AO) {
  int qs = blockIdx.x;
  int hb = blockIdx.y; int h = hb & 7, b = hb >> 3;
  int t = threadIdx.x;
  __shared__ float qv[32];
  __shared__ float sc[512];
  __shared__ float red[256];
  const size_t baseQ = ((size_t)(b*512 + qs))*RK + h*32;
  if (t < 32) qv[t] = Q[baseQ + t];
  __syncthreads();
  int nk = qs + 1;
  const float scale = 0.17677669529663687f;  // 1/sqrt(32)
  for (int k = t; k < nk; k += 256) {
    const float* kr = K + ((size_t)(b*512 + k))*RK + h*32;
    float s = 0.f;
    #pragma unroll
    for (int d = 0; d < 32; d += 4) {
      float4 kv = *reinterpret_cast<const float4*>(kr + d);
      s += kv.x*qv[d] + kv.y*qv[d+1] + kv.z*qv[d+2] + kv.w*qv[d+3];
    }
    sc[k] = s * scale;
  }
  __syncthreads();
  float m = NEGINF;
  for (int k = t; k < nk; k += 256) m = fmaxf(m, sc[k]);
  red[t] = m; __syncthreads();
  for (int o = 128; o > 0; o >>= 1) { if (t < o) red[t] = fmaxf(red[t], red[t+o]); __syncthreads(); }
  m = red[0];
  __syncthreads();
  float sloc = 0.f;
  for (int k = t; k < nk; k += 256) { float pp = expf(sc[k] - m); sc[k] = pp; sloc += pp; }
  red[t] = sloc; __syncthreads();
  for (int o = 128; o > 0; o >>= 1) { if (t < o) red[t] += red[t+o]; __syncthreads(); }
  float inv = 1.f / red[0];
  __syncthreads();
  int d = t & 31, c = t >> 5;
  float pa = 0.f;
  for (int k = c; k < nk; k += 8)
    pa += sc[k] * V[((size_t)(b*512 + k))*RK + h*32 + d];
  red[c*32 + d] = pa; __syncthreads();
  if (t < 32) {
    float o = 0.f;
    #pragma unroll
    for (int c2 = 0; c2 < 8; ++c2) o += red[c2*32 + t];
    AO[baseQ + t] = o * inv;
  }
}

// ------------- Transpose knowledge_K [8192][256] -> KT [256][8192] -------------
__global__ __launch_bounds__(256) void transpose_k(const float* __restrict__ kK,
                                                   float* __restrict__ KT) {
  __shared__ float tile[32][33];
  int bx = blockIdx.x, by = blockIdx.y;
  int tx = threadIdx.x & 31, ty = threadIdx.x >> 5;
  for (int r = ty; r < 32; r += 8)
    tile[r][tx] = kK[(size_t)(bx*32 + r)*RK + by*32 + tx];
  __syncthreads();
  for (int r = ty; r < 32; r += 8)
    KT[(size_t)(by*32 + r)*NKN + bx*32 + tx] = tile[tx][r];
}

// ------------- Knowledge scores: SGEMM 64 tok x 256 entries + per-chunk top-8 -------------
// grid: (32 token-tiles of 64, 32 chunks)
__global__ __launch_bounds__(256) void kscore(const float* __restrict__ Qm,
    const float* __restrict__ KT, float* __restrict__ cand_s, int* __restrict__ cand_i) {
  int tile = blockIdx.x, chunk = blockIdx.y, t = threadIdx.x;
  __shared__ __align__(16) char smem[64*258*4];  // 66048 B arena
  float (*Bs)[256] = reinterpret_cast<float(*)[256]>(smem);
  float (*At)[64]  = reinterpret_cast<float(*)[64]>(smem + 32*256*4);
  float (*sc)[258] = reinterpret_cast<float(*)[258]>(smem);
  float acc[8][8];
  #pragma unroll
  for (int i = 0; i < 8; ++i)
    #pragma unroll
    for (int j = 0; j < 8; ++j) acc[i][j] = 0.f;
  int tr = t >> 5, tc = t & 31;
  int ar0 = t & 63,        akc0 = (t >> 6) * 4;
  int ar1 = (t+256) & 63,  akc1 = ((t+256) >> 6) * 4;
  for (int k0 = 0; k0 < RK; k0 += 32) {
    #pragma unroll
    for (int it = 0; it < 8; ++it) {
      int f = it*1024 + t*4;
      gl_lds16(KT + (size_t)(k0 + (f >> 8))*NKN + chunk*256 + (f & 255), &Bs[0][0] + f);
    }
    {
      float4 v0 = *reinterpret_cast<const float4*>(Qm + (size_t)(tile*64 + ar0)*RK + k0 + akc0);
      float4 v1 = *reinterpret_cast<const float4*>(Qm + (size_t)(tile*64 + ar1)*RK + k0 + akc1);
      At[akc0+0][ar0] = v0.x; At[akc0+1][ar0] = v0.y; At[akc0+2][ar0] = v0.z; At[akc0+3][ar0] = v0.w;
      At[akc1+0][ar1] = v1.x; At[akc1+1][ar1] = v1.y; At[akc1+2][ar1] = v1.z; At[akc1+3][ar1] = v1.w;
    }
    __syncthreads();
    #pragma unroll 4
    for (int kk = 0; kk < 32; ++kk) {
      float4 a0 = *reinterpret_cast<const float4*>(&At[kk][tr*8]);
      float4 a1 = *reinterpret_cast<const float4*>(&At[kk][tr*8 + 4]);
      float4 b0 = *reinterpret_cast<const float4*>(&Bs[kk][tc*4]);
      float4 b1 = *reinterpret_cast<const float4*>(&Bs[kk][128 + tc*4]);
      float a[8] = {a0.x,a0.y,a0.z,a0.w,a1.x,a1.y,a1.z,a1.w};
      float b[8] = {b0.x,b0.y,b0.z,b0.w,b1.x,b1.y,b1.z,b1.w};
      #pragma unroll
      for (int i = 0; i < 8; ++i)
        #pragma unroll
        for (int j = 0; j < 8; ++j)
          acc[i][j] = fmaf(a[i], b[j], acc[i][j]);
    }
    __syncthreads();
  }
  // reuse arena for scores (barrier above guarantees all reads done)
  #pragma unroll
  for (int i = 0; i < 8; ++i)
    #pragma unroll
    for (int j = 0; j < 4; ++j) {
      sc[tr*8 + i][tc*4 + j]       = acc[i][j];
      sc[tr*8 + i][128 + tc*4 + j] = acc[i][j+4];
    }
  __syncthreads();
  // per-token top-8 over this chunk's 256 entries
  int lane = t & 63, wv = t >> 6;
  for (int s = 0; s < 16; ++s) {
    int tok = wv*16 + s;
    float v0 = sc[tok][lane], v1 = sc[tok][lane+64], v2 = sc[tok][lane+128], v3 = sc[tok][lane+192];
    size_t cbase = ((size_t)(tile*64 + tok)*KCH + chunk)*KK;
    #pragma unroll
    for (int iter = 0; iter < KK; ++iter) {
      float mv = v0; int mp = lane;
      if (v1 > mv) { mv = v1; mp = lane+64; }
      if (v2 > mv) { mv = v2; mp = lane+128; }
      if (v3 > mv) { mv = v3; mp = lane+192; }
      #pragma unroll
      for (int off = 32; off > 0; off >>= 1) {
        float ov = __shfl_xor(mv, off); int op = __shfl_xor(mp, off);
        if (ov > mv || (ov == mv && op < mp)) { mv = ov; mp = op; }
      }
      if ((mp & 63) == lane) {
        int j = mp >> 6;
        if (j == 0) v0 = NEGINF; else if (j == 1) v1 = NEGINF;
        else if (j == 2) v2 = NEGINF; else v3 = NEGINF;
      }
      if (lane == 0) { cand_s[cbase + iter] = mv; cand_i[cbase + iter] = chunk*256 + mp; }
    }
  }
}

// ------------- Knowledge merge: 256 candidates -> top-8, softmax, V gather -------------
__global__ __launch_bounds__(256) void knowledge_merge(const float* __restrict__ cand_s,
    const int* __restrict__ cand_i, const float* __restrict__ kV, float* __restrict__ xout) {
  int tok = blockIdx.x, t = threadIdx.x;
  __shared__ float s_sc[256];
  __shared__ int   s_ix[256];
  __shared__ float w8[KK];
  __shared__ int   i8[KK];
  s_sc[t] = cand_s[(size_t)tok*256 + t];
  s_ix[t] = cand_i[(size_t)tok*256 + t];
  __syncthreads();
  if (t < 64) {
    float v0 = s_sc[t], v1 = s_sc[t+64], v2 = s_sc[t+128], v3 = s_sc[t+192];
    float tops[KK]; int tpos[KK];
    #pragma unroll
    for (int iter = 0; iter < KK; ++iter) {
      float mv = v0; int mp = t;
      if (v1 > mv) { mv = v1; mp = t+64; }
      if (v2 > mv) { mv = v2; mp = t+128; }
      if (v3 > mv) { mv = v3; mp = t+192; }
      #pragma unroll
      for (int off = 32; off > 0; off >>= 1) {
        float ov = __shfl_xor(mv, off); int op = __shfl_xor(mp, off);
        if (ov > mv || (ov == mv && op < mp)) { mv = ov; mp = op; }
      }
      tops[iter] = mv; tpos[iter] = mp;
      if ((mp & 63) == t) {
        int j = mp >> 6;
        if (j == 0) v0 = NEGINF; else if (j == 1) v1 = NEGINF;
        else if (j == 2) v2 = NEGINF; else v3 = NEGINF;
      }
    }
    if (t == 0) {
      const float kscale = 1.f/16.f;  // 1/sqrt(256)
      float mx = tops[0]*kscale, se = 0.f, ex[KK];
      #pragma unroll
      for (int k = 0; k < KK; ++k) { ex[k] = expf(tops[k]*kscale - mx); se += ex[k]; }
      float inv = 1.f / se;
      #pragma unroll
      for (int k = 0; k < KK; ++k) { w8[k] = ex[k]*inv; i8[k] = s_ix[tpos[k]]; }
    }
  }
  __syncthreads();
  size_t orow = (size_t)tok * DM;
  float4 o = *reinterpret_cast<const float4*>(xout + orow + t*4);
  #pragma unroll
  for (int k = 0; k < KK; ++k) {
    float w = w8[k];
    const float4 v4 = *reinterpret_cast<const float4*>(kV + (size_t)i8[k]*DM + t*4);
    o.x += w*v4.x; o.y += w*v4.y; o.z += w*v4.z; o.w += w*v4.w;
  }
  *reinterpret_cast<float4*>(xout + orow + t*4) = o;
}

extern "C" void kernel_launch(void* const* d_in, const int* in_sizes, int n_in,
                              void* d_out, int out_size, void* d_ws, size_t ws_size,
                              hipStream_t stream) {
  const float* x  = (const float*)d_in[0];
  const float* cn = (const float*)d_in[2];
  const float* en = (const float*)d_in[3];
  const float* kK = (const float*)d_in[4];
  const float* kV = (const float*)d_in[5];
  const float* rq = (const float*)d_in[6];
  const float* rk = (const float*)d_in[7];
  const float* rv = (const float*)d_in[8];
  const float* ro = (const float*)d_in[9];
  const float* rm = (const float*)d_in[10];
  const float* g1 = (const float*)d_in[11];
  const float* b1 = (const float*)d_in[12];
  const float* g2 = (const float*)d_in[13];
  const float* b2 = (const float*)d_in[14];
  float* out = (float*)d_out;

  char* p = (char*)d_ws;
  auto alloc = [&](size_t bytes) { char* r = p; p += (bytes + 255) & ~(size_t)255; return r; };
  float* h    = (float*)alloc((size_t)BS*DM*4);
  float* h2   = (float*)alloc((size_t)BS*DM*4);
  float* KT   = (float*)alloc((size_t)RK*NKN*4);
  float* Q    = (float*)alloc((size_t)BS*RK*4);   // Q,Kb,Vb,Qm contiguous for one memset
  float* Kb   = (float*)alloc((size_t)BS*RK*4);
  float* Vb   = (float*)alloc((size_t)BS*RK*4);
  float* Qm   = (float*)alloc((size_t)BS*RK*4);
  float* AO   = (float*)alloc((size_t)BS*RK*4);
  float* w_all= (float*)alloc((size_t)3*BS*CK*4);
  float* w_o  = (float*)alloc((size_t)BS*EK*4);
  float* w_m  = (float*)alloc((size_t)BS*CK*4);
  float* cand_s = (float*)alloc((size_t)BS*KCH*KK*4);
  int*   cand_i = (int*)  alloc((size_t)BS*KCH*KK*4);
  int* lists  = (int*)alloc((size_t)5*64*BS*4);   // [q,k,v,o,m]
  int* counts = (int*)alloc((size_t)5*64*4);

  int *listo = lists + 3*64*BS, *listm = lists + 4*64*BS;
  int *co = counts + 192, *cm = counts + 256;

  hipMemsetAsync(counts, 0, 5*64*4, stream);
  hipMemsetAsync(Q, 0, (size_t)BS*RK*4*4, stream);  // zeros Q, Kb, Vb, Qm

  ln_kernel<<<BS, 256, 0, stream>>>(x, g1, b1, h);

  router3<<<BS, 256, 0, stream>>>(h, rq, rk, rv, w_all, lists, counts);
  ggemm_f32<DM, RK, CK><<<dim3(16, 3, 64), 256, 0, stream>>>(h, cn, w_all, lists, counts, Q);

  attn_kernel<<<dim3(512, 32), 256, 0, stream>>>(Q, Kb, Vb, AO);

  hipMemcpyAsync(out, x, (size_t)BS*DM*4, hipMemcpyDeviceToDevice, stream);  // out = x

  router_topk<RK, EK><<<BS, 256, 0, stream>>>(AO, ro, w_o, listo, co);
  ggemm_f32<RK, DM, EK><<<dim3(16, 4, 64), 256, 0, stream>>>(AO, en, w_o, listo, co, out); // out = x1

  ln_kernel<<<BS, 256, 0, stream>>>(out, g2, b2, h2);
  router_topk<DM, CK><<<BS, 256, 0, stream>>>(h2, rm, w_m, listm, cm);
  ggemm_f32<DM, RK, CK><<<dim3(16, 1, 64), 256, 0, stream>>>(h2, cn, w_m, listm, cm, Qm);

  transpose_k<<<dim3(NKN/32, RK/32), 256, 0, stream>>>(kK, KT);
  kscore<<<dim3(BS/64, KCH), 256, 0, stream>>>(Qm, KT, cand_s, cand_i);
  knowledge_merge<<<BS, 256, 0, stream>>>(cand_s, cand_i, kV, out);  // out = x1 + mem_out
}

// Round 7
// 1921.231 us; speedup vs baseline: 1.6134x; 1.3739x over previous
//
#include <hip/hip_runtime.h>

#define BS   2048     // B*S tokens
#define DM   1024     // D_MODEL
#define RK   256      // RANK
#define NKN  8192     // N_KNOWLEDGE
#define CK   8        // COMPRESS_TOP_K
#define EK   4        // EXPAND_TOP_K
#define KK   8        // KNOWLEDGE_K
#define KCH  32       // knowledge chunks of 256

#define NEGINF -1e30f

// ---------------- LayerNorm: one block per row of 1024 ----------------
__global__ __launch_bounds__(256) void ln_kernel(const float* __restrict__ xin,
    const float* __restrict__ g, const float* __restrict__ bb, float* __restrict__ out) {
  int row = blockIdx.x, t = threadIdx.x;
  __shared__ float red[256];
  const float4 v = *reinterpret_cast<const float4*>(xin + (size_t)row*DM + t*4);
  red[t] = v.x + v.y + v.z + v.w;
  __syncthreads();
  for (int o = 128; o > 0; o >>= 1) { if (t < o) red[t] += red[t+o]; __syncthreads(); }
  float mu = red[0] * (1.f/DM);
  __syncthreads();
  float dx = v.x-mu, dy = v.y-mu, dz = v.z-mu, dw = v.w-mu;
  red[t] = dx*dx + dy*dy + dz*dz + dw*dw;
  __syncthreads();
  for (int o = 128; o > 0; o >>= 1) { if (t < o) red[t] += red[t+o]; __syncthreads(); }
  float rs = rsqrtf(red[0]*(1.f/DM) + 1e-5f);
  float4 gv = *reinterpret_cast<const float4*>(g + t*4);
  float4 bv = *reinterpret_cast<const float4*>(bb + t*4);
  float4 o4 = make_float4(dx*rs*gv.x+bv.x, dy*rs*gv.y+bv.y, dz*rs*gv.z+bv.z, dw*rs*gv.w+bv.w);
  *reinterpret_cast<float4*>(out + (size_t)row*DM + t*4) = o4;
}

// ---- wave-parallel top-k over 64 scores held one-per-lane ----
template<int TOPK>
__device__ inline void wave_topk64(float bv, int lane, float* tops, int* tidx) {
  #pragma unroll
  for (int k = 0; k < TOPK; ++k) {
    float mv = bv; int mp = lane;
    #pragma unroll
    for (int off = 32; off > 0; off >>= 1) {
      float ov = __shfl_xor(mv, off); int op = __shfl_xor(mp, off);
      if (ov > mv || (ov == mv && op < mp)) { mv = ov; mp = op; }
    }
    tops[k] = mv; tidx[k] = mp;
    if (lane == mp) bv = NEGINF;
  }
}

// ------------- Generic router -------------
template<int DIM, int TOPK>
__global__ __launch_bounds__(256) void router_topk(const float* __restrict__ xin,
    const float* __restrict__ rw, float* __restrict__ w_out,
    int* __restrict__ lists, int* __restrict__ counts) {
  int token = blockIdx.x, t = threadIdx.x;
  __shared__ float part[4][64];
  int n = t & 63, c = t >> 6;
  const int CH = DIM / 4;
  const float* xr = xin + (size_t)token*DIM + c*CH;
  const float* wr = rw  + (size_t)n*DIM + c*CH;
  float p = 0.f;
  for (int j = 0; j < CH; j += 4) {
    float4 a = *reinterpret_cast<const float4*>(xr + j);
    float4 b = *reinterpret_cast<const float4*>(wr + j);
    p += a.x*b.x + a.y*b.y + a.z*b.z + a.w*b.w;
  }
  part[c][n] = p;
  __syncthreads();
  if (t < 64) {
    float bv = part[0][t] + part[1][t] + part[2][t] + part[3][t];
    float tops[TOPK]; int tidx[TOPK];
    wave_topk64<TOPK>(bv, t, tops, tidx);
    if (t == 0) {
      float mx = tops[0], se = 0.f, ex[TOPK];
      #pragma unroll
      for (int k = 0; k < TOPK; ++k) { ex[k] = expf(tops[k] - mx); se += ex[k]; }
      float inv = 1.f / se;
      #pragma unroll
      for (int k = 0; k < TOPK; ++k) {
        w_out[token*TOPK + k] = ex[k] * inv;
        int pos = atomicAdd(&counts[tidx[k]], 1);
        lists[tidx[k]*BS + pos] = token*TOPK + k;
      }
    }
  }
}

// ------------- Fused QKV router -------------
__global__ __launch_bounds__(256) void router3(const float* __restrict__ xin,
    const float* __restrict__ w0, const float* __restrict__ w1, const float* __restrict__ w2,
    float* __restrict__ w_all, int* __restrict__ lists, int* __restrict__ counts) {
  int token = blockIdx.x, t = threadIdx.x;
  __shared__ float part[3][4][64];
  int n = t & 63, c = t >> 6;
  const int CH = DM / 4;
  const float* xr = xin + (size_t)token*DM + c*CH;
  const float* a0 = w0 + (size_t)n*DM + c*CH;
  const float* a1 = w1 + (size_t)n*DM + c*CH;
  const float* a2 = w2 + (size_t)n*DM + c*CH;
  float p0 = 0.f, p1 = 0.f, p2 = 0.f;
  for (int j = 0; j < CH; j += 4) {
    float4 a  = *reinterpret_cast<const float4*>(xr + j);
    float4 b0 = *reinterpret_cast<const float4*>(a0 + j);
    float4 b1 = *reinterpret_cast<const float4*>(a1 + j);
    float4 b2 = *reinterpret_cast<const float4*>(a2 + j);
    p0 += a.x*b0.x + a.y*b0.y + a.z*b0.z + a.w*b0.w;
    p1 += a.x*b1.x + a.y*b1.y + a.z*b1.z + a.w*b1.w;
    p2 += a.x*b2.x + a.y*b2.y + a.z*b2.z + a.w*b2.w;
  }
  part[0][c][n] = p0; part[1][c][n] = p1; part[2][c][n] = p2;
  __syncthreads();
  int wv = t >> 6, lane = t & 63;
  if (wv < 3) {
    float bv = part[wv][0][lane] + part[wv][1][lane] + part[wv][2][lane] + part[wv][3][lane];
    float tops[CK]; int tidx[CK];
    wave_topk64<CK>(bv, lane, tops, tidx);
    if (lane == 0) {
      float* wo = w_all + (size_t)wv*BS*CK;
      int* lst  = lists  + (size_t)wv*64*BS;
      int* cnt  = counts + wv*64;
      float mx = tops[0], se = 0.f, ex[CK];
      #pragma unroll
      for (int k = 0; k < CK; ++k) { ex[k] = expf(tops[k] - mx); se += ex[k]; }
      float inv = 1.f / se;
      #pragma unroll
      for (int k = 0; k < CK; ++k) {
        wo[token*CK + k] = ex[k] * inv;
        int pos = atomicAdd(&cnt[tidx[k]], 1);
        lst[tidx[k]*BS + pos] = token*CK + k;
      }
    }
  }
}

// ------------- Grouped expert SGEMM: 64 tok x 256 col, BK=16, 8x8/thread -------------
// 21 KB LDS -> high occupancy; conflict-free split (cols tc*4 and 128+tc*4);
// loads issued before barrier (latency hides under previous compute phase).
// grid: (expert, token_chunk, which*COLCH + cc)
template<int KDIM, int NCOLT, int TK>
__global__ __launch_bounds__(256) void ggemm_f32(const float* __restrict__ xin,
    const float* __restrict__ neurons, const float* __restrict__ w_all,
    const int* __restrict__ lists, const int* __restrict__ counts,
    float* __restrict__ out) {
  constexpr int COLCH = NCOLT / 256;
  int e = blockIdx.x;
  int which = blockIdx.z / COLCH, cc = blockIdx.z % COLCH;
  int cnt = counts[which*64 + e];
  int base = blockIdx.y * 64;
  if (base >= cnt) return;
  const int* list_e = lists + ((size_t)which*64 + e)*BS;
  const float* wvp = w_all + (size_t)which*BS*TK;
  int t = threadIdx.x;
  __shared__ __align__(16) float Bs[16][256];
  __shared__ __align__(16) float At[16][64];
  __shared__ int   toks[64];
  __shared__ float wts[64];
  if (t < 64) {
    int idx = base + t;
    if (idx < cnt) { int e2 = list_e[idx]; toks[t] = e2 / TK; wts[t] = wvp[e2]; }
    else           { toks[t] = -1; wts[t] = 0.f; }
  }
  __syncthreads();
  float acc[8][8];
  #pragma unroll
  for (int i = 0; i < 8; ++i)
    #pragma unroll
    for (int j = 0; j < 8; ++j) acc[i][j] = 0.f;
  int tr = t >> 5, tc = t & 31;
  const float* W = neurons + (size_t)e*KDIM*NCOLT + cc*256;
  // A-staging: thread t loads token ar, k-offset akc..akc+3
  int ar = t & 63, akc = (t >> 6) * 4;
  int tokA = toks[ar];
  const float* Arow = xin + (size_t)(tokA >= 0 ? tokA : 0)*KDIM + akc;

  for (int k0 = 0; k0 < KDIM; k0 += 16) {
    // issue global loads first (overlap with other waves' compute)
    float4 b0r, b1r, b2r, b3r;
    {
      int f0 = t*4;
      b0r = *reinterpret_cast<const float4*>(W + (size_t)(k0 + (f0>>8))*NCOLT + (f0&255));
      int f1 = 1024 + t*4;
      b1r = *reinterpret_cast<const float4*>(W + (size_t)(k0 + (f1>>8))*NCOLT + (f1&255));
      int f2 = 2048 + t*4;
      b2r = *reinterpret_cast<const float4*>(W + (size_t)(k0 + (f2>>8))*NCOLT + (f2&255));
      int f3 = 3072 + t*4;
      b3r = *reinterpret_cast<const float4*>(W + (size_t)(k0 + (f3>>8))*NCOLT + (f3&255));
    }
    float4 av = *reinterpret_cast<const float4*>(Arow + k0);
    if (tokA < 0) av = make_float4(0.f, 0.f, 0.f, 0.f);
    __syncthreads();   // previous compute done reading LDS
    {
      int f0 = t*4;
      *reinterpret_cast<float4*>(&Bs[0][0] + f0)        = b0r;
      *reinterpret_cast<float4*>(&Bs[0][0] + f0 + 1024) = b1r;
      *reinterpret_cast<float4*>(&Bs[0][0] + f0 + 2048) = b2r;
      *reinterpret_cast<float4*>(&Bs[0][0] + f0 + 3072) = b3r;
      At[akc+0][ar] = av.x; At[akc+1][ar] = av.y;
      At[akc+2][ar] = av.z; At[akc+3][ar] = av.w;
    }
    __syncthreads();
    #pragma unroll
    for (int kk = 0; kk < 16; ++kk) {
      float4 a0 = *reinterpret_cast<const float4*>(&At[kk][tr*8]);
      float4 a1 = *reinterpret_cast<const float4*>(&At[kk][tr*8 + 4]);
      float4 p0 = *reinterpret_cast<const float4*>(&Bs[kk][tc*4]);
      float4 p1 = *reinterpret_cast<const float4*>(&Bs[kk][128 + tc*4]);
      float a[8] = {a0.x,a0.y,a0.z,a0.w,a1.x,a1.y,a1.z,a1.w};
      float b[8] = {p0.x,p0.y,p0.z,p0.w,p1.x,p1.y,p1.z,p1.w};
      #pragma unroll
      for (int i = 0; i < 8; ++i)
        #pragma unroll
        for (int j = 0; j < 8; ++j)
          acc[i][j] = fmaf(a[i], b[j], acc[i][j]);
    }
  }
  #pragma unroll
  for (int i = 0; i < 8; ++i) {
    int r = tr*8 + i;
    int tok = toks[r];
    if (tok < 0) continue;
    float wt = wts[r];
    float* orow = out + ((size_t)which*BS + tok)*NCOLT + cc*256;
    #pragma unroll
    for (int j = 0; j < 4; ++j) {
      atomicAdd(&orow[tc*4 + j],       wt * acc[i][j]);
      atomicAdd(&orow[128 + tc*4 + j], wt * acc[i][j+4]);
    }
  }
}

// ------------- Attention: one block per (q, head*batch) -------------
__global__ __launch_bounds__(256) void attn_kernel(const float* __restrict__ Q,
    const float* __restrict__ K, const float* __restrict__ V, float* __restrict__ AO) {
  int qs = blockIdx.x;
  int hb = blockIdx.y; int h = hb & 7, b = hb >> 3;
  int t = threadIdx.x;
  __shared__ float qv[32];
  __shared__ float sc[512];
  __shared__ float red[256];
  const size_t baseQ = ((size_t)(b*512 + qs))*RK + h*32;
  if (t < 32) qv[t] = Q[baseQ + t];
  __syncthreads();
  int nk = qs + 1;
  const float scale = 0.17677669529663687f;  // 1/sqrt(32)
  for (int k = t; k < nk; k += 256) {
    const float* kr = K + ((size_t)(b*512 + k))*RK + h*32;
    float s = 0.f;
    #pragma unroll
    for (int d = 0; d < 32; d += 4) {
      float4 kv = *reinterpret_cast<const float4*>(kr + d);
      s += kv.x*qv[d] + kv.y*qv[d+1] + kv.z*qv[d+2] + kv.w*qv[d+3];
    }
    sc[k] = s * scale;
  }
  __syncthreads();
  float m = NEGINF;
  for (int k = t; k < nk; k += 256) m = fmaxf(m, sc[k]);
  red[t] = m; __syncthreads();
  for (int o = 128; o > 0; o >>= 1) { if (t < o) red[t] = fmaxf(red[t], red[t+o]); __syncthreads(); }
  m = red[0];
  __syncthreads();
  float sloc = 0.f;
  for (int k = t; k < nk; k += 256) { float pp = expf(sc[k] - m); sc[k] = pp; sloc += pp; }
  red[t] = sloc; __syncthreads();
  for (int o = 128; o > 0; o >>= 1) { if (t < o) red[t] += red[t+o]; __syncthreads(); }
  float inv = 1.f / red[0];
  __syncthreads();
  int d = t & 31, c = t >> 5;
  float pa = 0.f;
  for (int k = c; k < nk; k += 8)
    pa += sc[k] * V[((size_t)(b*512 + k))*RK + h*32 + d];
  red[c*32 + d] = pa; __syncthreads();
  if (t < 32) {
    float o = 0.f;
    #pragma unroll
    for (int c2 = 0; c2 < 8; ++c2) o += red[c2*32 + t];
    AO[baseQ + t] = o * inv;
  }
}

// ------------- Transpose knowledge_K [8192][256] -> KT [256][8192] -------------
__global__ __launch_bounds__(256) void transpose_k(const float* __restrict__ kK,
                                                   float* __restrict__ KT) {
  __shared__ float tile[32][33];
  int bx = blockIdx.x, by = blockIdx.y;
  int tx = threadIdx.x & 31, ty = threadIdx.x >> 5;
  for (int r = ty; r < 32; r += 8)
    tile[r][tx] = kK[(size_t)(bx*32 + r)*RK + by*32 + tx];
  __syncthreads();
  for (int r = ty; r < 32; r += 8)
    KT[(size_t)(by*32 + r)*NKN + bx*32 + tx] = tile[tx][r];
}

// ------------- Knowledge scores: SGEMM 64 tok x 256 + REGISTER top-8 per chunk -------------
// grid: (32 token-tiles of 64, 32 chunks). No LDS score arena; top-8 via 32-lane shuffles.
__global__ __launch_bounds__(256) void kscore(const float* __restrict__ Qm,
    const float* __restrict__ KT, float* __restrict__ cand_s, int* __restrict__ cand_i) {
  int tile = blockIdx.x, chunk = blockIdx.y, t = threadIdx.x;
  __shared__ __align__(16) float Bs[16][256];
  __shared__ __align__(16) float At[16][64];
  float acc[8][8];
  #pragma unroll
  for (int i = 0; i < 8; ++i)
    #pragma unroll
    for (int j = 0; j < 8; ++j) acc[i][j] = 0.f;
  int tr = t >> 5, tc = t & 31;
  int ar = t & 63, akc = (t >> 6) * 4;
  const float* Arow = Qm + (size_t)(tile*64 + ar)*RK + akc;
  const float* W = KT + chunk*256;
  for (int k0 = 0; k0 < RK; k0 += 16) {
    float4 b0r, b1r, b2r, b3r;
    {
      int f0 = t*4;
      b0r = *reinterpret_cast<const float4*>(W + (size_t)(k0 + (f0>>8))*NKN + (f0&255));
      int f1 = 1024 + t*4;
      b1r = *reinterpret_cast<const float4*>(W + (size_t)(k0 + (f1>>8))*NKN + (f1&255));
      int f2 = 2048 + t*4;
      b2r = *reinterpret_cast<const float4*>(W + (size_t)(k0 + (f2>>8))*NKN + (f2&255));
      int f3 = 3072 + t*4;
      b3r = *reinterpret_cast<const float4*>(W + (size_t)(k0 + (f3>>8))*NKN + (f3&255));
    }
    float4 av = *reinterpret_cast<const float4*>(Arow + k0);
    __syncthreads();
    {
      int f0 = t*4;
      *reinterpret_cast<float4*>(&Bs[0][0] + f0)        = b0r;
      *reinterpret_cast<float4*>(&Bs[0][0] + f0 + 1024) = b1r;
      *reinterpret_cast<float4*>(&Bs[0][0] + f0 + 2048) = b2r;
      *reinterpret_cast<float4*>(&Bs[0][0] + f0 + 3072) = b3r;
      At[akc+0][ar] = av.x; At[akc+1][ar] = av.y;
      At[akc+2][ar] = av.z; At[akc+3][ar] = av.w;
    }
    __syncthreads();
    #pragma unroll
    for (int kk = 0; kk < 16; ++kk) {
      float4 a0 = *reinterpret_cast<const float4*>(&At[kk][tr*8]);
      float4 a1 = *reinterpret_cast<const float4*>(&At[kk][tr*8 + 4]);
      float4 p0 = *reinterpret_cast<const float4*>(&Bs[kk][tc*4]);
      float4 p1 = *reinterpret_cast<const float4*>(&Bs[kk][128 + tc*4]);
      float a[8] = {a0.x,a0.y,a0.z,a0.w,a1.x,a1.y,a1.z,a1.w};
      float b[8] = {p0.x,p0.y,p0.z,p0.w,p1.x,p1.y,p1.z,p1.w};
      #pragma unroll
      for (int i = 0; i < 8; ++i)
        #pragma unroll
        for (int j = 0; j < 8; ++j)
          acc[i][j] = fmaf(a[i], b[j], acc[i][j]);
    }
  }
  // per-token top-8: token row tr*8+i owned by the 32 lanes sharing tr (a half-wave).
  // col of acc[i][j]: j<4 -> tc*4+j ; j>=4 -> 128+tc*4+(j-4). 32-lane shfl_xor argmax.
  #pragma unroll
  for (int i = 0; i < 8; ++i) {
    float v0 = acc[i][0], v1 = acc[i][1], v2 = acc[i][2], v3 = acc[i][3];
    float v4 = acc[i][4], v5 = acc[i][5], v6 = acc[i][6], v7 = acc[i][7];
    float outs[KK]; int outi[KK];
    #pragma unroll
    for (int iter = 0; iter < KK; ++iter) {
      // local max over 8 named scalars (first-wins on ties -> lowest col)
      float mv = v0; int mj = 0;
      if (v1 > mv) { mv = v1; mj = 1; }
      if (v2 > mv) { mv = v2; mj = 2; }
      if (v3 > mv) { mv = v3; mj = 3; }
      if (v4 > mv) { mv = v4; mj = 4; }
      if (v5 > mv) { mv = v5; mj = 5; }
      if (v6 > mv) { mv = v6; mj = 6; }
      if (v7 > mv) { mv = v7; mj = 7; }
      int mp = (mj < 4) ? (tc*4 + mj) : (128 + tc*4 + (mj-4));
      #pragma unroll
      for (int off = 16; off > 0; off >>= 1) {
        float ov = __shfl_xor(mv, off); int op = __shfl_xor(mp, off);
        if (ov > mv || (ov == mv && op < mp)) { mv = ov; mp = op; }
      }
      outs[iter] = mv; outi[iter] = mp;
      // invalidate the winning slot in its owner lane
      int own_tc = (mp < 128) ? (mp >> 2) : ((mp - 128) >> 2);
      int own_j  = (mp < 128) ? (mp & 3) : (4 + (mp & 3));
      if (tc == own_tc) {
        if      (own_j == 0) v0 = NEGINF;
        else if (own_j == 1) v1 = NEGINF;
        else if (own_j == 2) v2 = NEGINF;
        else if (own_j == 3) v3 = NEGINF;
        else if (own_j == 4) v4 = NEGINF;
        else if (own_j == 5) v5 = NEGINF;
        else if (own_j == 6) v6 = NEGINF;
        else                 v7 = NEGINF;
      }
    }
    if (tc == 0) {
      int tok = tile*64 + tr*8 + i;
      size_t cbase = ((size_t)tok*KCH + chunk)*KK;
      #pragma unroll
      for (int k = 0; k < KK; ++k) {
        cand_s[cbase + k] = outs[k];
        cand_i[cbase + k] = chunk*256 + outi[k];
      }
    }
  }
}

// ------------- Knowledge merge: 256 candidates -> top-8, softmax, V gather -------------
__global__ __launch_bounds__(256) void knowledge_merge(const float* __restrict__ cand_s,
    const int* __restrict__ cand_i, const float* __restrict__ kV, float* __restrict__ xout) {
  int tok = blockIdx.x, t = threadIdx.x;
  __shared__ float s_sc[256];
  __shared__ int   s_ix[256];
  __shared__ float w8[KK];
  __shared__ int   i8[KK];
  s_sc[t] = cand_s[(size_t)tok*256 + t];
  s_ix[t] = cand_i[(size_t)tok*256 + t];
  __syncthreads();
  if (t < 64) {
    float v0 = s_sc[t], v1 = s_sc[t+64], v2 = s_sc[t+128], v3 = s_sc[t+192];
    float tops[KK]; int tpos[KK];
    #pragma unroll
    for (int iter = 0; iter < KK; ++iter) {
      float mv = v0; int mp = t;
      if (v1 > mv) { mv = v1; mp = t+64; }
      if (v2 > mv) { mv = v2; mp = t+128; }
      if (v3 > mv) { mv = v3; mp = t+192; }
      #pragma unroll
      for (int off = 32; off > 0; off >>= 1) {
        float ov = __shfl_xor(mv, off); int op = __shfl_xor(mp, off);
        if (ov > mv || (ov == mv && op < mp)) { mv = ov; mp = op; }
      }
      tops[iter] = mv; tpos[iter] = mp;
      if ((mp & 63) == t) {
        int j = mp >> 6;
        if (j == 0) v0 = NEGINF; else if (j == 1) v1 = NEGINF;
        else if (j == 2) v2 = NEGINF; else v3 = NEGINF;
      }
    }
    if (t == 0) {
      const float kscale = 1.f/16.f;  // 1/sqrt(256)
      float mx = tops[0]*kscale, se = 0.f, ex[KK];
      #pragma unroll
      for (int k = 0; k < KK; ++k) { ex[k] = expf(tops[k]*kscale - mx); se += ex[k]; }
      float inv = 1.f / se;
      #pragma unroll
      for (int k = 0; k < KK; ++k) { w8[k] = ex[k]*inv; i8[k] = s_ix[tpos[k]]; }
    }
  }
  __syncthreads();
  size_t orow = (size_t)tok * DM;
  float4 o = *reinterpret_cast<const float4*>(xout + orow + t*4);
  #pragma unroll
  for (int k = 0; k < KK; ++k) {
    float w = w8[k];
    const float4 v4 = *reinterpret_cast<const float4*>(kV + (size_t)i8[k]*DM + t*4);
    o.x += w*v4.x; o.y += w*v4.y; o.z += w*v4.z; o.w += w*v4.w;
  }
  *reinterpret_cast<float4*>(xout + orow + t*4) = o;
}

extern "C" void kernel_launch(void* const* d_in, const int* in_sizes, int n_in,
                              void* d_out, int out_size, void* d_ws, size_t ws_size,
                              hipStream_t stream) {
  const float* x  = (const float*)d_in[0];
  const float* cn = (const float*)d_in[2];
  const float* en = (const float*)d_in[3];
  const float* kK = (const float*)d_in[4];
  const float* kV = (const float*)d_in[5];
  const float* rq = (const float*)d_in[6];
  const float* rk = (const float*)d_in[7];
  const float* rv = (const float*)d_in[8];
  const float* ro = (const float*)d_in[9];
  const float* rm = (const float*)d_in[10];
  const float* g1 = (const float*)d_in[11];
  const float* b1 = (const float*)d_in[12];
  const float* g2 = (const float*)d_in[13];
  const float* b2 = (const float*)d_in[14];
  float* out = (float*)d_out;

  char* p = (char*)d_ws;
  auto alloc = [&](size_t bytes) { char* r = p; p += (bytes + 255) & ~(size_t)255; return r; };
  float* h    = (float*)alloc((size_t)BS*DM*4);
  float* h2   = (float*)alloc((size_t)BS*DM*4);
  float* KT   = (float*)alloc((size_t)RK*NKN*4);
  float* Q    = (float*)alloc((size_t)BS*RK*4);   // Q,Kb,Vb,Qm contiguous for one memset
  float* Kb   = (float*)alloc((size_t)BS*RK*4);
  float* Vb   = (float*)alloc((size_t)BS*RK*4);
  float* Qm   = (float*)alloc((size_t)BS*RK*4);
  float* AO   = (float*)alloc((size_t)BS*RK*4);
  float* w_all= (float*)alloc((size_t)3*BS*CK*4);
  float* w_o  = (float*)alloc((size_t)BS*EK*4);
  float* w_m  = (float*)alloc((size_t)BS*CK*4);
  float* cand_s = (float*)alloc((size_t)BS*KCH*KK*4);
  int*   cand_i = (int*)  alloc((size_t)BS*KCH*KK*4);
  int* lists  = (int*)alloc((size_t)5*64*BS*4);   // [q,k,v,o,m]
  int* counts = (int*)alloc((size_t)5*64*4);

  int *listo = lists + 3*64*BS, *listm = lists + 4*64*BS;
  int *co = counts + 192, *cm = counts + 256;

  hipMemsetAsync(counts, 0, 5*64*4, stream);
  hipMemsetAsync(Q, 0, (size_t)BS*RK*4*4, stream);  // zeros Q, Kb, Vb, Qm

  ln_kernel<<<BS, 256, 0, stream>>>(x, g1, b1, h);

  router3<<<BS, 256, 0, stream>>>(h, rq, rk, rv, w_all, lists, counts);
  ggemm_f32<DM, RK, CK><<<dim3(64, 16, 3), 256, 0, stream>>>(h, cn, w_all, lists, counts, Q);

  attn_kernel<<<dim3(512, 32), 256, 0, stream>>>(Q, Kb, Vb, AO);

  hipMemcpyAsync(out, x, (size_t)BS*DM*4, hipMemcpyDeviceToDevice, stream);  // out = x

  router_topk<RK, EK><<<BS, 256, 0, stream>>>(AO, ro, w_o, listo, co);
  ggemm_f32<RK, DM, EK><<<dim3(64, 16, 4), 256, 0, stream>>>(AO, en, w_o, listo, co, out); // out = x1

  ln_kernel<<<BS, 256, 0, stream>>>(out, g2, b2, h2);
  router_topk<DM, CK><<<BS, 256, 0, stream>>>(h2, rm, w_m, listm, cm);
  ggemm_f32<DM, RK, CK><<<dim3(64, 16, 1), 256, 0, stream>>>(h2, cn, w_m, listm, cm, Qm);

  transpose_k<<<dim3(NKN/32, RK/32), 256, 0, stream>>>(kK, KT);
  kscore<<<dim3(BS/64, KCH), 256, 0, stream>>>(Qm, KT, cand_s, cand_i);
  knowledge_merge<<<BS, 256, 0, stream>>>(cand_s, cand_i, kV, out);  // out = x1 + mem_out
}

// Round 8
// 1874.035 us; speedup vs baseline: 1.6541x; 1.0252x over previous
//
#include <hip/hip_runtime.h>

#define BS   2048     // B*S tokens
#define DM   1024     // D_MODEL
#define RK   256      // RANK
#define NKN  8192     // N_KNOWLEDGE
#define CK   8        // COMPRESS_TOP_K
#define EK   4        // EXPAND_TOP_K
#define KK   8        // KNOWLEDGE_K
#define KCH  32       // knowledge chunks of 256

#define NEGINF -1e30f

typedef __attribute__((ext_vector_type(8))) short short8;   // 8 bf16
typedef __attribute__((ext_vector_type(4))) float f32x4;

// ---- wave-parallel top-k over 64 scores held one-per-lane ----
template<int TOPK>
__device__ inline void wave_topk64(float bv, int lane, float* tops, int* tidx) {
  #pragma unroll
  for (int k = 0; k < TOPK; ++k) {
    float mv = bv; int mp = lane;
    #pragma unroll
    for (int off = 32; off > 0; off >>= 1) {
      float ov = __shfl_xor(mv, off); int op = __shfl_xor(mp, off);
      if (ov > mv || (ov == mv && op < mp)) { mv = ov; mp = op; }
    }
    tops[k] = mv; tidx[k] = mp;
    if (lane == mp) bv = NEGINF;
  }
}

// ---- router tail: softmax top-k weights + expert-list append (lane 0 only) ----
template<int TOPK>
__device__ inline void router_commit(int token, const float* tops, const int* tidx,
    float* w_out, int* lists, int* counts) {
  float mx = tops[0], se = 0.f, ex[TOPK];
  #pragma unroll
  for (int k = 0; k < TOPK; ++k) { ex[k] = expf(tops[k] - mx); se += ex[k]; }
  float inv = 1.f / se;
  #pragma unroll
  for (int k = 0; k < TOPK; ++k) {
    w_out[token*TOPK + k] = ex[k] * inv;
    int pos = atomicAdd(&counts[tidx[k]], 1);
    lists[tidx[k]*BS + pos] = token*TOPK + k;
  }
}

// ------------- Fused LN1 + QKV router: one block per token -------------
__global__ __launch_bounds__(256) void ln_router3(const float* __restrict__ xin,
    const float* __restrict__ g, const float* __restrict__ bb, float* __restrict__ hout,
    const float* __restrict__ w0, const float* __restrict__ w1, const float* __restrict__ w2,
    float* __restrict__ w_all, int* __restrict__ lists, int* __restrict__ counts) {
  int row = blockIdx.x, t = threadIdx.x;
  __shared__ float red[256];
  __shared__ __align__(16) float hrow[DM];
  __shared__ float part[3][4][64];
  const float4 v = *reinterpret_cast<const float4*>(xin + (size_t)row*DM + t*4);
  red[t] = v.x + v.y + v.z + v.w;
  __syncthreads();
  for (int o = 128; o > 0; o >>= 1) { if (t < o) red[t] += red[t+o]; __syncthreads(); }
  float mu = red[0] * (1.f/DM);
  __syncthreads();
  float dx = v.x-mu, dy = v.y-mu, dz = v.z-mu, dw = v.w-mu;
  red[t] = dx*dx + dy*dy + dz*dz + dw*dw;
  __syncthreads();
  for (int o = 128; o > 0; o >>= 1) { if (t < o) red[t] += red[t+o]; __syncthreads(); }
  float rs = rsqrtf(red[0]*(1.f/DM) + 1e-5f);
  float4 gv = *reinterpret_cast<const float4*>(g + t*4);
  float4 bv = *reinterpret_cast<const float4*>(bb + t*4);
  float4 o4 = make_float4(dx*rs*gv.x+bv.x, dy*rs*gv.y+bv.y, dz*rs*gv.z+bv.z, dw*rs*gv.w+bv.w);
  *reinterpret_cast<float4*>(hout + (size_t)row*DM + t*4) = o4;
  *reinterpret_cast<float4*>(&hrow[t*4]) = o4;
  __syncthreads();
  // router: 64-lane groups read hrow broadcast, 64 experts x 4 chunks
  int n = t & 63, c = t >> 6;
  const int CH = DM / 4;
  const float* xr = &hrow[c*CH];
  const float* a0 = w0 + (size_t)n*DM + c*CH;
  const float* a1 = w1 + (size_t)n*DM + c*CH;
  const float* a2 = w2 + (size_t)n*DM + c*CH;
  float p0 = 0.f, p1 = 0.f, p2 = 0.f;
  for (int j = 0; j < CH; j += 4) {
    float4 a  = *reinterpret_cast<const float4*>(xr + j);
    float4 b0 = *reinterpret_cast<const float4*>(a0 + j);
    float4 b1 = *reinterpret_cast<const float4*>(a1 + j);
    float4 b2 = *reinterpret_cast<const float4*>(a2 + j);
    p0 += a.x*b0.x + a.y*b0.y + a.z*b0.z + a.w*b0.w;
    p1 += a.x*b1.x + a.y*b1.y + a.z*b1.z + a.w*b1.w;
    p2 += a.x*b2.x + a.y*b2.y + a.z*b2.z + a.w*b2.w;
  }
  part[0][c][n] = p0; part[1][c][n] = p1; part[2][c][n] = p2;
  __syncthreads();
  int wv = t >> 6, lane = t & 63;
  if (wv < 3) {
    float bvv = part[wv][0][lane] + part[wv][1][lane] + part[wv][2][lane] + part[wv][3][lane];
    float tops[CK]; int tidx[CK];
    wave_topk64<CK>(bvv, lane, tops, tidx);
    if (lane == 0)
      router_commit<CK>(row, tops, tidx, w_all + (size_t)wv*BS*CK,
                        lists + (size_t)wv*64*BS, counts + wv*64);
  }
}

// ------------- Fused LN2 + memory router: one block per token -------------
__global__ __launch_bounds__(256) void ln_router1(const float* __restrict__ xin,
    const float* __restrict__ g, const float* __restrict__ bb, float* __restrict__ hout,
    const float* __restrict__ rw,
    float* __restrict__ w_out, int* __restrict__ lists, int* __restrict__ counts) {
  int row = blockIdx.x, t = threadIdx.x;
  __shared__ float red[256];
  __shared__ __align__(16) float hrow[DM];
  __shared__ float part[4][64];
  const float4 v = *reinterpret_cast<const float4*>(xin + (size_t)row*DM + t*4);
  red[t] = v.x + v.y + v.z + v.w;
  __syncthreads();
  for (int o = 128; o > 0; o >>= 1) { if (t < o) red[t] += red[t+o]; __syncthreads(); }
  float mu = red[0] * (1.f/DM);
  __syncthreads();
  float dx = v.x-mu, dy = v.y-mu, dz = v.z-mu, dw = v.w-mu;
  red[t] = dx*dx + dy*dy + dz*dz + dw*dw;
  __syncthreads();
  for (int o = 128; o > 0; o >>= 1) { if (t < o) red[t] += red[t+o]; __syncthreads(); }
  float rs = rsqrtf(red[0]*(1.f/DM) + 1e-5f);
  float4 gv = *reinterpret_cast<const float4*>(g + t*4);
  float4 bv = *reinterpret_cast<const float4*>(bb + t*4);
  float4 o4 = make_float4(dx*rs*gv.x+bv.x, dy*rs*gv.y+bv.y, dz*rs*gv.z+bv.z, dw*rs*gv.w+bv.w);
  *reinterpret_cast<float4*>(hout + (size_t)row*DM + t*4) = o4;
  *reinterpret_cast<float4*>(&hrow[t*4]) = o4;
  __syncthreads();
  int n = t & 63, c = t >> 6;
  const int CH = DM / 4;
  const float* xr = &hrow[c*CH];
  const float* wr = rw + (size_t)n*DM + c*CH;
  float p = 0.f;
  for (int j = 0; j < CH; j += 4) {
    float4 a = *reinterpret_cast<const float4*>(xr + j);
    float4 b = *reinterpret_cast<const float4*>(wr + j);
    p += a.x*b.x + a.y*b.y + a.z*b.z + a.w*b.w;
  }
  part[c][n] = p;
  __syncthreads();
  if (t < 64) {
    float bvv = part[0][t] + part[1][t] + part[2][t] + part[3][t];
    float tops[CK]; int tidx[CK];
    wave_topk64<CK>(bvv, t, tops, tidx);
    if (t == 0) router_commit<CK>(row, tops, tidx, w_out, lists, counts);
  }
}

// ------------- Generic router (expand router on AO) -------------
template<int DIM, int TOPK>
__global__ __launch_bounds__(256) void router_topk(const float* __restrict__ xin,
    const float* __restrict__ rw, float* __restrict__ w_out,
    int* __restrict__ lists, int* __restrict__ counts) {
  int token = blockIdx.x, t = threadIdx.x;
  __shared__ float part[4][64];
  int n = t & 63, c = t >> 6;
  const int CH = DIM / 4;
  const float* xr = xin + (size_t)token*DIM + c*CH;
  const float* wr = rw  + (size_t)n*DIM + c*CH;
  float p = 0.f;
  for (int j = 0; j < CH; j += 4) {
    float4 a = *reinterpret_cast<const float4*>(xr + j);
    float4 b = *reinterpret_cast<const float4*>(wr + j);
    p += a.x*b.x + a.y*b.y + a.z*b.z + a.w*b.w;
  }
  part[c][n] = p;
  __syncthreads();
  if (t < 64) {
    float bv = part[0][t] + part[1][t] + part[2][t] + part[3][t];
    float tops[TOPK]; int tidx[TOPK];
    wave_topk64<TOPK>(bv, t, tops, tidx);
    if (t == 0) router_commit<TOPK>(token, tops, tidx, w_out, lists, counts);
  }
}

// ------------- Grouped expert SGEMM: 64 tok x 256 col, BK=16, 8x8/thread -------------
template<int KDIM, int NCOLT, int TK>
__global__ __launch_bounds__(256) void ggemm_f32(const float* __restrict__ xin,
    const float* __restrict__ neurons, const float* __restrict__ w_all,
    const int* __restrict__ lists, const int* __restrict__ counts,
    float* __restrict__ out) {
  constexpr int COLCH = NCOLT / 256;
  int e = blockIdx.x;
  int which = blockIdx.z / COLCH, cc = blockIdx.z % COLCH;
  int cnt = counts[which*64 + e];
  int base = blockIdx.y * 64;
  if (base >= cnt) return;
  const int* list_e = lists + ((size_t)which*64 + e)*BS;
  const float* wvp = w_all + (size_t)which*BS*TK;
  int t = threadIdx.x;
  __shared__ __align__(16) float Bs[16][256];
  __shared__ __align__(16) float At[16][64];
  __shared__ int   toks[64];
  __shared__ float wts[64];
  if (t < 64) {
    int idx = base + t;
    if (idx < cnt) { int e2 = list_e[idx]; toks[t] = e2 / TK; wts[t] = wvp[e2]; }
    else           { toks[t] = -1; wts[t] = 0.f; }
  }
  __syncthreads();
  float acc[8][8];
  #pragma unroll
  for (int i = 0; i < 8; ++i)
    #pragma unroll
    for (int j = 0; j < 8; ++j) acc[i][j] = 0.f;
  int tr = t >> 5, tc = t & 31;
  const float* W = neurons + (size_t)e*KDIM*NCOLT + cc*256;
  int ar = t & 63, akc = (t >> 6) * 4;
  int tokA = toks[ar];
  const float* Arow = xin + (size_t)(tokA >= 0 ? tokA : 0)*KDIM + akc;

  for (int k0 = 0; k0 < KDIM; k0 += 16) {
    float4 b0r, b1r, b2r, b3r;
    {
      int f0 = t*4;
      b0r = *reinterpret_cast<const float4*>(W + (size_t)(k0 + (f0>>8))*NCOLT + (f0&255));
      int f1 = 1024 + t*4;
      b1r = *reinterpret_cast<const float4*>(W + (size_t)(k0 + (f1>>8))*NCOLT + (f1&255));
      int f2 = 2048 + t*4;
      b2r = *reinterpret_cast<const float4*>(W + (size_t)(k0 + (f2>>8))*NCOLT + (f2&255));
      int f3 = 3072 + t*4;
      b3r = *reinterpret_cast<const float4*>(W + (size_t)(k0 + (f3>>8))*NCOLT + (f3&255));
    }
    float4 av = *reinterpret_cast<const float4*>(Arow + k0);
    if (tokA < 0) av = make_float4(0.f, 0.f, 0.f, 0.f);
    __syncthreads();
    {
      int f0 = t*4;
      *reinterpret_cast<float4*>(&Bs[0][0] + f0)        = b0r;
      *reinterpret_cast<float4*>(&Bs[0][0] + f0 + 1024) = b1r;
      *reinterpret_cast<float4*>(&Bs[0][0] + f0 + 2048) = b2r;
      *reinterpret_cast<float4*>(&Bs[0][0] + f0 + 3072) = b3r;
      At[akc+0][ar] = av.x; At[akc+1][ar] = av.y;
      At[akc+2][ar] = av.z; At[akc+3][ar] = av.w;
    }
    __syncthreads();
    #pragma unroll
    for (int kk = 0; kk < 16; ++kk) {
      float4 a0 = *reinterpret_cast<const float4*>(&At[kk][tr*8]);
      float4 a1 = *reinterpret_cast<const float4*>(&At[kk][tr*8 + 4]);
      float4 p0 = *reinterpret_cast<const float4*>(&Bs[kk][tc*4]);
      float4 p1 = *reinterpret_cast<const float4*>(&Bs[kk][128 + tc*4]);
      float a[8] = {a0.x,a0.y,a0.z,a0.w,a1.x,a1.y,a1.z,a1.w};
      float b[8] = {p0.x,p0.y,p0.z,p0.w,p1.x,p1.y,p1.z,p1.w};
      #pragma unroll
      for (int i = 0; i < 8; ++i)
        #pragma unroll
        for (int j = 0; j < 8; ++j)
          acc[i][j] = fmaf(a[i], b[j], acc[i][j]);
    }
  }
  #pragma unroll
  for (int i = 0; i < 8; ++i) {
    int r = tr*8 + i;
    int tok = toks[r];
    if (tok < 0) continue;
    float wt = wts[r];
    float* orow = out + ((size_t)which*BS + tok)*NCOLT + cc*256;
    #pragma unroll
    for (int j = 0; j < 4; ++j) {
      atomicAdd(&orow[tc*4 + j],       wt * acc[i][j]);
      atomicAdd(&orow[128 + tc*4 + j], wt * acc[i][j+4]);
    }
  }
}

// ------------- Attention: one block per (q, head*batch) -------------
__global__ __launch_bounds__(256) void attn_kernel(const float* __restrict__ Q,
    const float* __restrict__ K, const float* __restrict__ V, float* __restrict__ AO) {
  int qs = blockIdx.x;
  int hb = blockIdx.y; int h = hb & 7, b = hb >> 3;
  int t = threadIdx.x;
  __shared__ float qv[32];
  __shared__ float sc[512];
  __shared__ float red[256];
  const size_t baseQ = ((size_t)(b*512 + qs))*RK + h*32;
  if (t < 32) qv[t] = Q[baseQ + t];
  __syncthreads();
  int nk = qs + 1;
  const float scale = 0.17677669529663687f;  // 1/sqrt(32)
  for (int k = t; k < nk; k += 256) {
    const float* kr = K + ((size_t)(b*512 + k))*RK + h*32;
    float s = 0.f;
    #pragma unroll
    for (int d = 0; d < 32; d += 4) {
      float4 kv = *reinterpret_cast<const float4*>(kr + d);
      s += kv.x*qv[d] + kv.y*qv[d+1] + kv.z*qv[d+2] + kv.w*qv[d+3];
    }
    sc[k] = s * scale;
  }
  __syncthreads();
  float m = NEGINF;
  for (int k = t; k < nk; k += 256) m = fmaxf(m, sc[k]);
  red[t] = m; __syncthreads();
  for (int o = 128; o > 0; o >>= 1) { if (t < o) red[t] = fmaxf(red[t], red[t+o]); __syncthreads(); }
  m = red[0];
  __syncthreads();
  float sloc = 0.f;
  for (int k = t; k < nk; k += 256) { float pp = expf(sc[k] - m); sc[k] = pp; sloc += pp; }
  red[t] = sloc; __syncthreads();
  for (int o = 128; o > 0; o >>= 1) { if (t < o) red[t] += red[t+o]; __syncthreads(); }
  float inv = 1.f / red[0];
  __syncthreads();
  int d = t & 31, c = t >> 5;
  float pa = 0.f;
  for (int k = c; k < nk; k += 8)
    pa += sc[k] * V[((size_t)(b*512 + k))*RK + h*32 + d];
  red[c*32 + d] = pa; __syncthreads();
  if (t < 32) {
    float o = 0.f;
    #pragma unroll
    for (int c2 = 0; c2 < 8; ++c2) o += red[c2*32 + t];
    AO[baseQ + t] = o * inv;
  }
}

// ------------- f32 -> bf16 (RTN), 8 elems/thread -------------
__global__ __launch_bounds__(256) void f2bf(const float* __restrict__ in,
                                            unsigned short* __restrict__ out, int n8) {
  int i = blockIdx.x*256 + threadIdx.x;
  if (i >= n8) return;
  float4 a = reinterpret_cast<const float4*>(in)[2*i];
  float4 b = reinterpret_cast<const float4*>(in)[2*i + 1];
  float v[8] = {a.x,a.y,a.z,a.w,b.x,b.y,b.z,b.w};
  unsigned u[8];
  #pragma unroll
  for (int j = 0; j < 8; ++j) {
    unsigned bits = __float_as_uint(v[j]);
    u[j] = (bits + 0x7fffu + ((bits >> 16) & 1u)) >> 16;
  }
  uint4 o;
  o.x = u[0] | (u[1] << 16); o.y = u[2] | (u[3] << 16);
  o.z = u[4] | (u[5] << 16); o.w = u[6] | (u[7] << 16);
  *reinterpret_cast<uint4*>(out + 8*i) = o;
}

// ------------- Knowledge scores via bf16 MFMA + per-chunk top-8 -------------
// D[ent][tok] = kK . Qm^T. Block: 32 tokens x 256 ents (one chunk), K=256.
// Wave w owns ents w*64..+63 (4 m-tiles) x 2 token-tiles. grid: (64 token-tiles, 32 chunks)
__global__ __launch_bounds__(256) void kscore_mfma(const unsigned short* __restrict__ Qmb,
    const unsigned short* __restrict__ kKb, float* __restrict__ cand_s, int* __restrict__ cand_i) {
  int tile = blockIdx.x, chunk = blockIdx.y;
  int t = threadIdx.x, w = t >> 6, l = t & 63;
  int lr = l & 15, lg = l >> 4;
  __shared__ float sc[32][265];   // [tok][ent] (+pad: 265%32=9 odd -> conflict-free spill)
  f32x4 acc[4][2];
  #pragma unroll
  for (int mi = 0; mi < 4; ++mi)
    #pragma unroll
    for (int ti = 0; ti < 2; ++ti) acc[mi][ti] = (f32x4)0.f;
  const unsigned short* Abase = kKb + ((size_t)(chunk*256 + w*64 + lr))*RK + lg*8;
  const unsigned short* Bbase = Qmb + ((size_t)(tile*32 + lr))*RK + lg*8;
  #pragma unroll
  for (int k0 = 0; k0 < RK; k0 += 32) {
    short8 af[4], bf[2];
    #pragma unroll
    for (int mi = 0; mi < 4; ++mi)
      af[mi] = *reinterpret_cast<const short8*>(Abase + (size_t)mi*16*RK + k0);
    #pragma unroll
    for (int ti = 0; ti < 2; ++ti)
      bf[ti] = *reinterpret_cast<const short8*>(Bbase + (size_t)ti*16*RK + k0);
    #pragma unroll
    for (int mi = 0; mi < 4; ++mi)
      #pragma unroll
      for (int ti = 0; ti < 2; ++ti)
        acc[mi][ti] = __builtin_amdgcn_mfma_f32_16x16x32_bf16(af[mi], bf[ti], acc[mi][ti], 0, 0, 0);
  }
  // spill: C row = ent_local = lg*4+reg (within m-tile), col = tok_local = lr (within n-tile)
  #pragma unroll
  for (int mi = 0; mi < 4; ++mi)
    #pragma unroll
    for (int ti = 0; ti < 2; ++ti)
      #pragma unroll
      for (int r = 0; r < 4; ++r)
        sc[ti*16 + lr][w*64 + mi*16 + lg*4 + r] = acc[mi][ti][r];
  __syncthreads();
  // per-token top-8 over this chunk's 256 entries (wave w: tokens w*8..+7)
  for (int s = 0; s < 8; ++s) {
    int tok = w*8 + s;
    float v0 = sc[tok][l], v1 = sc[tok][l+64], v2 = sc[tok][l+128], v3 = sc[tok][l+192];
    size_t cbase = ((size_t)(tile*32 + tok)*KCH + chunk)*KK;
    #pragma unroll
    for (int iter = 0; iter < KK; ++iter) {
      float mv = v0; int mp = l;
      if (v1 > mv) { mv = v1; mp = l+64; }
      if (v2 > mv) { mv = v2; mp = l+128; }
      if (v3 > mv) { mv = v3; mp = l+192; }
      #pragma unroll
      for (int off = 32; off > 0; off >>= 1) {
        float ov = __shfl_xor(mv, off); int op = __shfl_xor(mp, off);
        if (ov > mv || (ov == mv && op < mp)) { mv = ov; mp = op; }
      }
      if ((mp & 63) == l) {
        int j = mp >> 6;
        if (j == 0) v0 = NEGINF; else if (j == 1) v1 = NEGINF;
        else if (j == 2) v2 = NEGINF; else v3 = NEGINF;
      }
      if (l == 0) { cand_s[cbase + iter] = mv; cand_i[cbase + iter] = chunk*256 + mp; }
    }
  }
}

// ------------- Knowledge merge: 256 candidates -> top-8, softmax, V gather -------------
__global__ __launch_bounds__(256) void knowledge_merge(const float* __restrict__ cand_s,
    const int* __restrict__ cand_i, const float* __restrict__ kV, float* __restrict__ xout) {
  int tok = blockIdx.x, t = threadIdx.x;
  __shared__ float s_sc[256];
  __shared__ int   s_ix[256];
  __shared__ float w8[KK];
  __shared__ int   i8[KK];
  s_sc[t] = cand_s[(size_t)tok*256 + t];
  s_ix[t] = cand_i[(size_t)tok*256 + t];
  __syncthreads();
  if (t < 64) {
    float v0 = s_sc[t], v1 = s_sc[t+64], v2 = s_sc[t+128], v3 = s_sc[t+192];
    float tops[KK]; int tpos[KK];
    #pragma unroll
    for (int iter = 0; iter < KK; ++iter) {
      float mv = v0; int mp = t;
      if (v1 > mv) { mv = v1; mp = t+64; }
      if (v2 > mv) { mv = v2; mp = t+128; }
      if (v3 > mv) { mv = v3; mp = t+192; }
      #pragma unroll
      for (int off = 32; off > 0; off >>= 1) {
        float ov = __shfl_xor(mv, off); int op = __shfl_xor(mp, off);
        if (ov > mv || (ov == mv && op < mp)) { mv = ov; mp = op; }
      }
      tops[iter] = mv; tpos[iter] = mp;
      if ((mp & 63) == t) {
        int j = mp >> 6;
        if (j == 0) v0 = NEGINF; else if (j == 1) v1 = NEGINF;
        else if (j == 2) v2 = NEGINF; else v3 = NEGINF;
      }
    }
    if (t == 0) {
      const float kscale = 1.f/16.f;  // 1/sqrt(256)
      float mx = tops[0]*kscale, se = 0.f, ex[KK];
      #pragma unroll
      for (int k = 0; k < KK; ++k) { ex[k] = expf(tops[k]*kscale - mx); se += ex[k]; }
      float inv = 1.f / se;
      #pragma unroll
      for (int k = 0; k < KK; ++k) { w8[k] = ex[k]*inv; i8[k] = s_ix[tpos[k]]; }
    }
  }
  __syncthreads();
  size_t orow = (size_t)tok * DM;
  float4 o = *reinterpret_cast<const float4*>(xout + orow + t*4);
  #pragma unroll
  for (int k = 0; k < KK; ++k) {
    float w = w8[k];
    const float4 v4 = *reinterpret_cast<const float4*>(kV + (size_t)i8[k]*DM + t*4);
    o.x += w*v4.x; o.y += w*v4.y; o.z += w*v4.z; o.w += w*v4.w;
  }
  *reinterpret_cast<float4*>(xout + orow + t*4) = o;
}

extern "C" void kernel_launch(void* const* d_in, const int* in_sizes, int n_in,
                              void* d_out, int out_size, void* d_ws, size_t ws_size,
                              hipStream_t stream) {
  const float* x  = (const float*)d_in[0];
  const float* cn = (const float*)d_in[2];
  const float* en = (const float*)d_in[3];
  const float* kK = (const float*)d_in[4];
  const float* kV = (const float*)d_in[5];
  const float* rq = (const float*)d_in[6];
  const float* rk = (const float*)d_in[7];
  const float* rv = (const float*)d_in[8];
  const float* ro = (const float*)d_in[9];
  const float* rm = (const float*)d_in[10];
  const float* g1 = (const float*)d_in[11];
  const float* b1 = (const float*)d_in[12];
  const float* g2 = (const float*)d_in[13];
  const float* b2 = (const float*)d_in[14];
  float* out = (float*)d_out;

  char* p = (char*)d_ws;
  auto alloc = [&](size_t bytes) { char* r = p; p += (bytes + 255) & ~(size_t)255; return r; };
  float* h    = (float*)alloc((size_t)BS*DM*4);
  float* h2   = (float*)alloc((size_t)BS*DM*4);
  float* Q    = (float*)alloc((size_t)BS*RK*4);   // Q,Kb,Vb,Qm contiguous for one memset
  float* Kb   = (float*)alloc((size_t)BS*RK*4);
  float* Vb   = (float*)alloc((size_t)BS*RK*4);
  float* Qm   = (float*)alloc((size_t)BS*RK*4);
  float* AO   = (float*)alloc((size_t)BS*RK*4);
  float* w_all= (float*)alloc((size_t)3*BS*CK*4);
  float* w_o  = (float*)alloc((size_t)BS*EK*4);
  float* w_m  = (float*)alloc((size_t)BS*CK*4);
  float* cand_s = (float*)alloc((size_t)BS*KCH*KK*4);
  int*   cand_i = (int*)  alloc((size_t)BS*KCH*KK*4);
  unsigned short* Qmb = (unsigned short*)alloc((size_t)BS*RK*2);
  unsigned short* kKb = (unsigned short*)alloc((size_t)NKN*RK*2);
  int* lists  = (int*)alloc((size_t)5*64*BS*4);   // [q,k,v,o,m]
  int* counts = (int*)alloc((size_t)5*64*4);

  int *listo = lists + 3*64*BS, *listm = lists + 4*64*BS;
  int *co = counts + 192, *cm = counts + 256;

  hipMemsetAsync(counts, 0, 5*64*4, stream);
  hipMemsetAsync(Q, 0, (size_t)BS*RK*4*4, stream);  // zeros Q, Kb, Vb, Qm

  f2bf<<<NKN*RK/8/256, 256, 0, stream>>>(kK, kKb, NKN*RK/8);  // independent; early

  ln_router3<<<BS, 256, 0, stream>>>(x, g1, b1, h, rq, rk, rv, w_all, lists, counts);
  ggemm_f32<DM, RK, CK><<<dim3(64, 16, 3), 256, 0, stream>>>(h, cn, w_all, lists, counts, Q);

  attn_kernel<<<dim3(512, 32), 256, 0, stream>>>(Q, Kb, Vb, AO);

  hipMemcpyAsync(out, x, (size_t)BS*DM*4, hipMemcpyDeviceToDevice, stream);  // out = x

  router_topk<RK, EK><<<BS, 256, 0, stream>>>(AO, ro, w_o, listo, co);
  ggemm_f32<RK, DM, EK><<<dim3(64, 16, 4), 256, 0, stream>>>(AO, en, w_o, listo, co, out); // out = x1

  ln_router1<<<BS, 256, 0, stream>>>(out, g2, b2, h2, rm, w_m, listm, cm);
  ggemm_f32<DM, RK, CK><<<dim3(64, 16, 1), 256, 0, stream>>>(h2, cn, w_m, listm, cm, Qm);

  f2bf<<<BS*RK/8/256, 256, 0, stream>>>(Qm, Qmb, BS*RK/8);
  kscore_mfma<<<dim3(BS/32, KCH), 256, 0, stream>>>(Qmb, kKb, cand_s, cand_i);
  knowledge_merge<<<BS, 256, 0, stream>>>(cand_s, cand_i, kV, out);  // out = x1 + mem_out
}

// Round 9
// 1673.228 us; speedup vs baseline: 1.8526x; 1.1200x over previous
//
#include <hip/hip_runtime.h>

#define BS   2048     // B*S tokens
#define DM   1024     // D_MODEL
#define RK   256      // RANK
#define NKN  8192     // N_KNOWLEDGE
#define CK   8        // COMPRESS_TOP_K
#define EK   4        // EXPAND_TOP_K
#define KK   8        // KNOWLEDGE_K
#define KCH  32       // knowledge chunks of 256

#define NEGINF -1e30f

typedef __attribute__((ext_vector_type(8))) short short8;   // 8 bf16
typedef __attribute__((ext_vector_type(4))) float f32x4;

__device__ __forceinline__ unsigned short bf16_rtn(float v) {
  unsigned bits = __float_as_uint(v);
  return (unsigned short)((bits + 0x7fffu + ((bits >> 16) & 1u)) >> 16);
}
__device__ __forceinline__ float bf16f(unsigned short u) {
  return __uint_as_float(((unsigned)u) << 16);
}
__device__ __forceinline__ void split2(float v, unsigned short& h, unsigned short& l) {
  h = bf16_rtn(v);
  l = bf16_rtn(v - bf16f(h));
}

// ---- wave-parallel top-k over 64 scores held one-per-lane ----
template<int TOPK>
__device__ inline void wave_topk64(float bv, int lane, float* tops, int* tidx) {
  #pragma unroll
  for (int k = 0; k < TOPK; ++k) {
    float mv = bv; int mp = lane;
    #pragma unroll
    for (int off = 32; off > 0; off >>= 1) {
      float ov = __shfl_xor(mv, off); int op = __shfl_xor(mp, off);
      if (ov > mv || (ov == mv && op < mp)) { mv = ov; mp = op; }
    }
    tops[k] = mv; tidx[k] = mp;
    if (lane == mp) bv = NEGINF;
  }
}

template<int TOPK>
__device__ inline void router_commit(int token, const float* tops, const int* tidx,
    float* w_out, int* lists, int* counts) {
  float mx = tops[0], se = 0.f, ex[TOPK];
  #pragma unroll
  for (int k = 0; k < TOPK; ++k) { ex[k] = expf(tops[k] - mx); se += ex[k]; }
  float inv = 1.f / se;
  #pragma unroll
  for (int k = 0; k < TOPK; ++k) {
    w_out[token*TOPK + k] = ex[k] * inv;
    int pos = atomicAdd(&counts[tidx[k]], 1);
    lists[tidx[k]*BS + pos] = token*TOPK + k;
  }
}

// ------------- Fused LN1 + QKV router; emits bf16 hi/lo split of h -------------
__global__ __launch_bounds__(256) void ln_router3(const float* __restrict__ xin,
    const float* __restrict__ g, const float* __restrict__ bb,
    unsigned short* __restrict__ hh, unsigned short* __restrict__ hl,
    const float* __restrict__ w0, const float* __restrict__ w1, const float* __restrict__ w2,
    float* __restrict__ w_all, int* __restrict__ lists, int* __restrict__ counts) {
  int row = blockIdx.x, t = threadIdx.x;
  __shared__ float red[256];
  __shared__ __align__(16) float hrow[DM];
  __shared__ float part[3][4][64];
  const float4 v = *reinterpret_cast<const float4*>(xin + (size_t)row*DM + t*4);
  red[t] = v.x + v.y + v.z + v.w;
  __syncthreads();
  for (int o = 128; o > 0; o >>= 1) { if (t < o) red[t] += red[t+o]; __syncthreads(); }
  float mu = red[0] * (1.f/DM);
  __syncthreads();
  float dx = v.x-mu, dy = v.y-mu, dz = v.z-mu, dw = v.w-mu;
  red[t] = dx*dx + dy*dy + dz*dz + dw*dw;
  __syncthreads();
  for (int o = 128; o > 0; o >>= 1) { if (t < o) red[t] += red[t+o]; __syncthreads(); }
  float rs = rsqrtf(red[0]*(1.f/DM) + 1e-5f);
  float4 gv = *reinterpret_cast<const float4*>(g + t*4);
  float4 bv = *reinterpret_cast<const float4*>(bb + t*4);
  float4 o4 = make_float4(dx*rs*gv.x+bv.x, dy*rs*gv.y+bv.y, dz*rs*gv.z+bv.z, dw*rs*gv.w+bv.w);
  ushort4 uh, ul;
  split2(o4.x, uh.x, ul.x); split2(o4.y, uh.y, ul.y);
  split2(o4.z, uh.z, ul.z); split2(o4.w, uh.w, ul.w);
  *reinterpret_cast<ushort4*>(hh + (size_t)row*DM + t*4) = uh;
  *reinterpret_cast<ushort4*>(hl + (size_t)row*DM + t*4) = ul;
  *reinterpret_cast<float4*>(&hrow[t*4]) = o4;
  __syncthreads();
  int n = t & 63, c = t >> 6;
  const int CH = DM / 4;
  const float* xr = &hrow[c*CH];
  const float* a0 = w0 + (size_t)n*DM + c*CH;
  const float* a1 = w1 + (size_t)n*DM + c*CH;
  const float* a2 = w2 + (size_t)n*DM + c*CH;
  float p0 = 0.f, p1 = 0.f, p2 = 0.f;
  for (int j = 0; j < CH; j += 4) {
    float4 a  = *reinterpret_cast<const float4*>(xr + j);
    float4 b0 = *reinterpret_cast<const float4*>(a0 + j);
    float4 b1 = *reinterpret_cast<const float4*>(a1 + j);
    float4 b2 = *reinterpret_cast<const float4*>(a2 + j);
    p0 += a.x*b0.x + a.y*b0.y + a.z*b0.z + a.w*b0.w;
    p1 += a.x*b1.x + a.y*b1.y + a.z*b1.z + a.w*b1.w;
    p2 += a.x*b2.x + a.y*b2.y + a.z*b2.z + a.w*b2.w;
  }
  part[0][c][n] = p0; part[1][c][n] = p1; part[2][c][n] = p2;
  __syncthreads();
  int wv = t >> 6, lane = t & 63;
  if (wv < 3) {
    float bvv = part[wv][0][lane] + part[wv][1][lane] + part[wv][2][lane] + part[wv][3][lane];
    float tops[CK]; int tidx[CK];
    wave_topk64<CK>(bvv, lane, tops, tidx);
    if (lane == 0)
      router_commit<CK>(row, tops, tidx, w_all + (size_t)wv*BS*CK,
                        lists + (size_t)wv*64*BS, counts + wv*64);
  }
}

// ------------- Fused LN2 + memory router; emits bf16 hi/lo split of h2 -------------
__global__ __launch_bounds__(256) void ln_router1(const float* __restrict__ xin,
    const float* __restrict__ g, const float* __restrict__ bb,
    unsigned short* __restrict__ hh, unsigned short* __restrict__ hl,
    const float* __restrict__ rw,
    float* __restrict__ w_out, int* __restrict__ lists, int* __restrict__ counts) {
  int row = blockIdx.x, t = threadIdx.x;
  __shared__ float red[256];
  __shared__ __align__(16) float hrow[DM];
  __shared__ float part[4][64];
  const float4 v = *reinterpret_cast<const float4*>(xin + (size_t)row*DM + t*4);
  red[t] = v.x + v.y + v.z + v.w;
  __syncthreads();
  for (int o = 128; o > 0; o >>= 1) { if (t < o) red[t] += red[t+o]; __syncthreads(); }
  float mu = red[0] * (1.f/DM);
  __syncthreads();
  float dx = v.x-mu, dy = v.y-mu, dz = v.z-mu, dw = v.w-mu;
  red[t] = dx*dx + dy*dy + dz*dz + dw*dw;
  __syncthreads();
  for (int o = 128; o > 0; o >>= 1) { if (t < o) red[t] += red[t+o]; __syncthreads(); }
  float rs = rsqrtf(red[0]*(1.f/DM) + 1e-5f);
  float4 gv = *reinterpret_cast<const float4*>(g + t*4);
  float4 bv = *reinterpret_cast<const float4*>(bb + t*4);
  float4 o4 = make_float4(dx*rs*gv.x+bv.x, dy*rs*gv.y+bv.y, dz*rs*gv.z+bv.z, dw*rs*gv.w+bv.w);
  ushort4 uh, ul;
  split2(o4.x, uh.x, ul.x); split2(o4.y, uh.y, ul.y);
  split2(o4.z, uh.z, ul.z); split2(o4.w, uh.w, ul.w);
  *reinterpret_cast<ushort4*>(hh + (size_t)row*DM + t*4) = uh;
  *reinterpret_cast<ushort4*>(hl + (size_t)row*DM + t*4) = ul;
  *reinterpret_cast<float4*>(&hrow[t*4]) = o4;
  __syncthreads();
  int n = t & 63, c = t >> 6;
  const int CH = DM / 4;
  const float* xr = &hrow[c*CH];
  const float* wr = rw + (size_t)n*DM + c*CH;
  float p = 0.f;
  for (int j = 0; j < CH; j += 4) {
    float4 a = *reinterpret_cast<const float4*>(xr + j);
    float4 b = *reinterpret_cast<const float4*>(wr + j);
    p += a.x*b.x + a.y*b.y + a.z*b.z + a.w*b.w;
  }
  part[c][n] = p;
  __syncthreads();
  if (t < 64) {
    float bvv = part[0][t] + part[1][t] + part[2][t] + part[3][t];
    float tops[CK]; int tidx[CK];
    wave_topk64<CK>(bvv, t, tops, tidx);
    if (t == 0) router_commit<CK>(row, tops, tidx, w_out, lists, counts);
  }
}

// ------------- Generic router (expand router on AO) -------------
template<int DIM, int TOPK>
__global__ __launch_bounds__(256) void router_topk(const float* __restrict__ xin,
    const float* __restrict__ rw, float* __restrict__ w_out,
    int* __restrict__ lists, int* __restrict__ counts) {
  int token = blockIdx.x, t = threadIdx.x;
  __shared__ float part[4][64];
  int n = t & 63, c = t >> 6;
  const int CH = DIM / 4;
  const float* xr = xin + (size_t)token*DIM + c*CH;
  const float* wr = rw  + (size_t)n*DIM + c*CH;
  float p = 0.f;
  for (int j = 0; j < CH; j += 4) {
    float4 a = *reinterpret_cast<const float4*>(xr + j);
    float4 b = *reinterpret_cast<const float4*>(wr + j);
    p += a.x*b.x + a.y*b.y + a.z*b.z + a.w*b.w;
  }
  part[c][n] = p;
  __syncthreads();
  if (t < 64) {
    float bv = part[0][t] + part[1][t] + part[2][t] + part[3][t];
    float tops[TOPK]; int tidx[TOPK];
    wave_topk64<TOPK>(bv, t, tops, tidx);
    if (t == 0) router_commit<TOPK>(token, tops, tidx, w_out, lists, counts);
  }
}

// ------------- cn [e][k][c] f32 -> cnT_hi/lo [e][c][k] bf16 (transpose+split) -------------
// grid: (32 kblk, 8 cblk, 64 e), block 256
__global__ __launch_bounds__(256) void cvt_cnT(const float* __restrict__ cn,
    unsigned short* __restrict__ th, unsigned short* __restrict__ tl) {
  __shared__ float tile[32][33];
  int kb = blockIdx.x*32, cb = blockIdx.y*32, e = blockIdx.z;
  int tx = threadIdx.x & 31, ty = threadIdx.x >> 5;
  const size_t ebase = (size_t)e * DM * RK;
  for (int r = ty; r < 32; r += 8)
    tile[r][tx] = cn[ebase + (size_t)(kb + r)*RK + cb + tx];
  __syncthreads();
  for (int r = ty; r < 32; r += 8) {
    float v = tile[tx][r];
    unsigned short h, l; split2(v, h, l);
    size_t o = (size_t)e*RK*DM + (size_t)(cb + r)*DM + kb + tx;
    th[o] = h; tl[o] = l;
  }
}

// ------------- Grouped compress GEMM via split-bf16 MFMA (fp32-accurate) -------------
// D[col][tok] = sum_k W^T[col][k] * x[tok][k];  3 products: AhBh + AhBl + AlBh.
// Block: 256 cols x 64 toks, K=1024, LDS-free. Wave w: cols w*64..+63.
// grid: (expert, token_chunk64, which)
__global__ __launch_bounds__(256) void ggemm_mfma(
    const unsigned short* __restrict__ xh, const unsigned short* __restrict__ xl,
    const unsigned short* __restrict__ WTh, const unsigned short* __restrict__ WTl,
    const float* __restrict__ w_all, const int* __restrict__ lists,
    const int* __restrict__ counts, float* __restrict__ out) {
  int e = blockIdx.x, which = blockIdx.z;
  int cnt = counts[which*64 + e];
  int base = blockIdx.y * 64;
  if (base >= cnt) return;
  const int* list_e = lists + ((size_t)which*64 + e)*BS;
  const float* wvp = w_all + (size_t)which*BS*CK;
  int t = threadIdx.x, w = t >> 6, l = t & 63, lr = l & 15, lg = l >> 4;
  __shared__ int   toks[64];
  __shared__ float wts[64];
  if (t < 64) {
    int idx = base + t;
    if (idx < cnt) { int e2 = list_e[idx]; toks[t] = e2 / CK; wts[t] = wvp[e2]; }
    else           { toks[t] = -1; wts[t] = 0.f; }
  }
  __syncthreads();
  f32x4 acc[4][4];
  #pragma unroll
  for (int mi = 0; mi < 4; ++mi)
    #pragma unroll
    for (int ni = 0; ni < 4; ++ni) acc[mi][ni] = (f32x4)0.f;
  const unsigned short* Ahb = WTh + ((size_t)e*RK + w*64 + lr)*DM + lg*8;
  const unsigned short* Alb = WTl + ((size_t)e*RK + w*64 + lr)*DM + lg*8;
  int tokn[4]; float wtn[4];
  const unsigned short *Bh[4], *Bl[4];
  #pragma unroll
  for (int ni = 0; ni < 4; ++ni) {
    tokn[ni] = toks[ni*16 + lr];
    wtn[ni]  = wts[ni*16 + lr];
    int tk = tokn[ni] >= 0 ? tokn[ni] : 0;
    Bh[ni] = xh + (size_t)tk*DM + lg*8;
    Bl[ni] = xl + (size_t)tk*DM + lg*8;
  }
  for (int k0 = 0; k0 < DM; k0 += 32) {
    short8 ah[4], al[4], bh[4], bl[4];
    #pragma unroll
    for (int mi = 0; mi < 4; ++mi) {
      ah[mi] = *reinterpret_cast<const short8*>(Ahb + (size_t)mi*16*DM + k0);
      al[mi] = *reinterpret_cast<const short8*>(Alb + (size_t)mi*16*DM + k0);
    }
    #pragma unroll
    for (int ni = 0; ni < 4; ++ni) {
      bh[ni] = *reinterpret_cast<const short8*>(Bh[ni] + k0);
      bl[ni] = *reinterpret_cast<const short8*>(Bl[ni] + k0);
    }
    #pragma unroll
    for (int mi = 0; mi < 4; ++mi)
      #pragma unroll
      for (int ni = 0; ni < 4; ++ni) {
        acc[mi][ni] = __builtin_amdgcn_mfma_f32_16x16x32_bf16(ah[mi], bh[ni], acc[mi][ni], 0, 0, 0);
        acc[mi][ni] = __builtin_amdgcn_mfma_f32_16x16x32_bf16(ah[mi], bl[ni], acc[mi][ni], 0, 0, 0);
        acc[mi][ni] = __builtin_amdgcn_mfma_f32_16x16x32_bf16(al[mi], bh[ni], acc[mi][ni], 0, 0, 0);
      }
  }
  // C: token = lane&15 (within n-tile), col = w*64 + mi*16 + lg*4 + r
  #pragma unroll
  for (int ni = 0; ni < 4; ++ni) {
    if (tokn[ni] < 0) continue;
    float wt = wtn[ni];
    float* orow = out + ((size_t)which*BS + tokn[ni])*RK;
    #pragma unroll
    for (int mi = 0; mi < 4; ++mi) {
      int col = w*64 + mi*16 + lg*4;
      #pragma unroll
      for (int r = 0; r < 4; ++r)
        atomicAdd(&orow[col + r], wt * acc[mi][ni][r]);
    }
  }
}

// ------------- Expand grouped SGEMM (fp32, unchanged structure) -------------
template<int KDIM, int NCOLT, int TK>
__global__ __launch_bounds__(256) void ggemm_f32(const float* __restrict__ xin,
    const float* __restrict__ neurons, const float* __restrict__ w_all,
    const int* __restrict__ lists, const int* __restrict__ counts,
    float* __restrict__ out) {
  constexpr int COLCH = NCOLT / 256;
  int e = blockIdx.x;
  int which = blockIdx.z / COLCH, cc = blockIdx.z % COLCH;
  int cnt = counts[which*64 + e];
  int base = blockIdx.y * 64;
  if (base >= cnt) return;
  const int* list_e = lists + ((size_t)which*64 + e)*BS;
  const float* wvp = w_all + (size_t)which*BS*TK;
  int t = threadIdx.x;
  __shared__ __align__(16) float Bs[16][256];
  __shared__ __align__(16) float At[16][64];
  __shared__ int   toks[64];
  __shared__ float wts[64];
  if (t < 64) {
    int idx = base + t;
    if (idx < cnt) { int e2 = list_e[idx]; toks[t] = e2 / TK; wts[t] = wvp[e2]; }
    else           { toks[t] = -1; wts[t] = 0.f; }
  }
  __syncthreads();
  float acc[8][8];
  #pragma unroll
  for (int i = 0; i < 8; ++i)
    #pragma unroll
    for (int j = 0; j < 8; ++j) acc[i][j] = 0.f;
  int tr = t >> 5, tc = t & 31;
  const float* W = neurons + (size_t)e*KDIM*NCOLT + cc*256;
  int ar = t & 63, akc = (t >> 6) * 4;
  int tokA = toks[ar];
  const float* Arow = xin + (size_t)(tokA >= 0 ? tokA : 0)*KDIM + akc;

  for (int k0 = 0; k0 < KDIM; k0 += 16) {
    float4 b0r, b1r, b2r, b3r;
    {
      int f0 = t*4;
      b0r = *reinterpret_cast<const float4*>(W + (size_t)(k0 + (f0>>8))*NCOLT + (f0&255));
      int f1 = 1024 + t*4;
      b1r = *reinterpret_cast<const float4*>(W + (size_t)(k0 + (f1>>8))*NCOLT + (f1&255));
      int f2 = 2048 + t*4;
      b2r = *reinterpret_cast<const float4*>(W + (size_t)(k0 + (f2>>8))*NCOLT + (f2&255));
      int f3 = 3072 + t*4;
      b3r = *reinterpret_cast<const float4*>(W + (size_t)(k0 + (f3>>8))*NCOLT + (f3&255));
    }
    float4 av = *reinterpret_cast<const float4*>(Arow + k0);
    if (tokA < 0) av = make_float4(0.f, 0.f, 0.f, 0.f);
    __syncthreads();
    {
      int f0 = t*4;
      *reinterpret_cast<float4*>(&Bs[0][0] + f0)        = b0r;
      *reinterpret_cast<float4*>(&Bs[0][0] + f0 + 1024) = b1r;
      *reinterpret_cast<float4*>(&Bs[0][0] + f0 + 2048) = b2r;
      *reinterpret_cast<float4*>(&Bs[0][0] + f0 + 3072) = b3r;
      At[akc+0][ar] = av.x; At[akc+1][ar] = av.y;
      At[akc+2][ar] = av.z; At[akc+3][ar] = av.w;
    }
    __syncthreads();
    #pragma unroll
    for (int kk = 0; kk < 16; ++kk) {
      float4 a0 = *reinterpret_cast<const float4*>(&At[kk][tr*8]);
      float4 a1 = *reinterpret_cast<const float4*>(&At[kk][tr*8 + 4]);
      float4 p0 = *reinterpret_cast<const float4*>(&Bs[kk][tc*4]);
      float4 p1 = *reinterpret_cast<const float4*>(&Bs[kk][128 + tc*4]);
      float a[8] = {a0.x,a0.y,a0.z,a0.w,a1.x,a1.y,a1.z,a1.w};
      float b[8] = {p0.x,p0.y,p0.z,p0.w,p1.x,p1.y,p1.z,p1.w};
      #pragma unroll
      for (int i = 0; i < 8; ++i)
        #pragma unroll
        for (int j = 0; j < 8; ++j)
          acc[i][j] = fmaf(a[i], b[j], acc[i][j]);
    }
  }
  #pragma unroll
  for (int i = 0; i < 8; ++i) {
    int r = tr*8 + i;
    int tok = toks[r];
    if (tok < 0) continue;
    float wt = wts[r];
    float* orow = out + ((size_t)which*BS + tok)*NCOLT + cc*256;
    #pragma unroll
    for (int j = 0; j < 4; ++j) {
      atomicAdd(&orow[tc*4 + j],       wt * acc[i][j]);
      atomicAdd(&orow[128 + tc*4 + j], wt * acc[i][j+4]);
    }
  }
}

// ------------- Attention: one block per (q, head*batch) -------------
__global__ __launch_bounds__(256) void attn_kernel(const float* __restrict__ Q,
    const float* __restrict__ K, const float* __restrict__ V, float* __restrict__ AO) {
  int qs = blockIdx.x;
  int hb = blockIdx.y; int h = hb & 7, b = hb >> 3;
  int t = threadIdx.x;
  __shared__ float qv[32];
  __shared__ float sc[512];
  __shared__ float red[256];
  const size_t baseQ = ((size_t)(b*512 + qs))*RK + h*32;
  if (t < 32) qv[t] = Q[baseQ + t];
  __syncthreads();
  int nk = qs + 1;
  const float scale = 0.17677669529663687f;  // 1/sqrt(32)
  for (int k = t; k < nk; k += 256) {
    const float* kr = K + ((size_t)(b*512 + k))*RK + h*32;
    float s = 0.f;
    #pragma unroll
    for (int d = 0; d < 32; d += 4) {
      float4 kv = *reinterpret_cast<const float4*>(kr + d);
      s += kv.x*qv[d] + kv.y*qv[d+1] + kv.z*qv[d+2] + kv.w*qv[d+3];
    }
    sc[k] = s * scale;
  }
  __syncthreads();
  float m = NEGINF;
  for (int k = t; k < nk; k += 256) m = fmaxf(m, sc[k]);
  red[t] = m; __syncthreads();
  for (int o = 128; o > 0; o >>= 1) { if (t < o) red[t] = fmaxf(red[t], red[t+o]); __syncthreads(); }
  m = red[0];
  __syncthreads();
  float sloc = 0.f;
  for (int k = t; k < nk; k += 256) { float pp = expf(sc[k] - m); sc[k] = pp; sloc += pp; }
  red[t] = sloc; __syncthreads();
  for (int o = 128; o > 0; o >>= 1) { if (t < o) red[t] += red[t+o]; __syncthreads(); }
  float inv = 1.f / red[0];
  __syncthreads();
  int d = t & 31, c = t >> 5;
  float pa = 0.f;
  for (int k = c; k < nk; k += 8)
    pa += sc[k] * V[((size_t)(b*512 + k))*RK + h*32 + d];
  red[c*32 + d] = pa; __syncthreads();
  if (t < 32) {
    float o = 0.f;
    #pragma unroll
    for (int c2 = 0; c2 < 8; ++c2) o += red[c2*32 + t];
    AO[baseQ + t] = o * inv;
  }
}

// ------------- f32 -> bf16 (RTN), 8 elems/thread -------------
__global__ __launch_bounds__(256) void f2bf(const float* __restrict__ in,
                                            unsigned short* __restrict__ out, int n8) {
  int i = blockIdx.x*256 + threadIdx.x;
  if (i >= n8) return;
  float4 a = reinterpret_cast<const float4*>(in)[2*i];
  float4 b = reinterpret_cast<const float4*>(in)[2*i + 1];
  float v[8] = {a.x,a.y,a.z,a.w,b.x,b.y,b.z,b.w};
  unsigned u[8];
  #pragma unroll
  for (int j = 0; j < 8; ++j) {
    unsigned bits = __float_as_uint(v[j]);
    u[j] = (bits + 0x7fffu + ((bits >> 16) & 1u)) >> 16;
  }
  uint4 o;
  o.x = u[0] | (u[1] << 16); o.y = u[2] | (u[3] << 16);
  o.z = u[4] | (u[5] << 16); o.w = u[6] | (u[7] << 16);
  *reinterpret_cast<uint4*>(out + 8*i) = o;
}

// ------------- Knowledge scores via bf16 MFMA + per-chunk top-8 -------------
__global__ __launch_bounds__(256) void kscore_mfma(const unsigned short* __restrict__ Qmb,
    const unsigned short* __restrict__ kKb, float* __restrict__ cand_s, int* __restrict__ cand_i) {
  int tile = blockIdx.x, chunk = blockIdx.y;
  int t = threadIdx.x, w = t >> 6, l = t & 63;
  int lr = l & 15, lg = l >> 4;
  __shared__ float sc[32][265];
  f32x4 acc[4][2];
  #pragma unroll
  for (int mi = 0; mi < 4; ++mi)
    #pragma unroll
    for (int ti = 0; ti < 2; ++ti) acc[mi][ti] = (f32x4)0.f;
  const unsigned short* Abase = kKb + ((size_t)(chunk*256 + w*64 + lr))*RK + lg*8;
  const unsigned short* Bbase = Qmb + ((size_t)(tile*32 + lr))*RK + lg*8;
  #pragma unroll
  for (int k0 = 0; k0 < RK; k0 += 32) {
    short8 af[4], bf[2];
    #pragma unroll
    for (int mi = 0; mi < 4; ++mi)
      af[mi] = *reinterpret_cast<const short8*>(Abase + (size_t)mi*16*RK + k0);
    #pragma unroll
    for (int ti = 0; ti < 2; ++ti)
      bf[ti] = *reinterpret_cast<const short8*>(Bbase + (size_t)ti*16*RK + k0);
    #pragma unroll
    for (int mi = 0; mi < 4; ++mi)
      #pragma unroll
      for (int ti = 0; ti < 2; ++ti)
        acc[mi][ti] = __builtin_amdgcn_mfma_f32_16x16x32_bf16(af[mi], bf[ti], acc[mi][ti], 0, 0, 0);
  }
  #pragma unroll
  for (int mi = 0; mi < 4; ++mi)
    #pragma unroll
    for (int ti = 0; ti < 2; ++ti)
      #pragma unroll
      for (int r = 0; r < 4; ++r)
        sc[ti*16 + lr][w*64 + mi*16 + lg*4 + r] = acc[mi][ti][r];
  __syncthreads();
  for (int s = 0; s < 8; ++s) {
    int tok = w*8 + s;
    float v0 = sc[tok][l], v1 = sc[tok][l+64], v2 = sc[tok][l+128], v3 = sc[tok][l+192];
    size_t cbase = ((size_t)(tile*32 + tok)*KCH + chunk)*KK;
    #pragma unroll
    for (int iter = 0; iter < KK; ++iter) {
      float mv = v0; int mp = l;
      if (v1 > mv) { mv = v1; mp = l+64; }
      if (v2 > mv) { mv = v2; mp = l+128; }
      if (v3 > mv) { mv = v3; mp = l+192; }
      #pragma unroll
      for (int off = 32; off > 0; off >>= 1) {
        float ov = __shfl_xor(mv, off); int op = __shfl_xor(mp, off);
        if (ov > mv || (ov == mv && op < mp)) { mv = ov; mp = op; }
      }
      if ((mp & 63) == l) {
        int j = mp >> 6;
        if (j == 0) v0 = NEGINF; else if (j == 1) v1 = NEGINF;
        else if (j == 2) v2 = NEGINF; else v3 = NEGINF;
      }
      if (l == 0) { cand_s[cbase + iter] = mv; cand_i[cbase + iter] = chunk*256 + mp; }
    }
  }
}

// ------------- Knowledge merge: 256 candidates -> top-8, softmax, V gather -------------
__global__ __launch_bounds__(256) void knowledge_merge(const float* __restrict__ cand_s,
    const int* __restrict__ cand_i, const float* __restrict__ kV, float* __restrict__ xout) {
  int tok = blockIdx.x, t = threadIdx.x;
  __shared__ float s_sc[256];
  __shared__ int   s_ix[256];
  __shared__ float w8[KK];
  __shared__ int   i8[KK];
  s_sc[t] = cand_s[(size_t)tok*256 + t];
  s_ix[t] = cand_i[(size_t)tok*256 + t];
  __syncthreads();
  if (t < 64) {
    float v0 = s_sc[t], v1 = s_sc[t+64], v2 = s_sc[t+128], v3 = s_sc[t+192];
    float tops[KK]; int tpos[KK];
    #pragma unroll
    for (int iter = 0; iter < KK; ++iter) {
      float mv = v0; int mp = t;
      if (v1 > mv) { mv = v1; mp = t+64; }
      if (v2 > mv) { mv = v2; mp = t+128; }
      if (v3 > mv) { mv = v3; mp = t+192; }
      #pragma unroll
      for (int off = 32; off > 0; off >>= 1) {
        float ov = __shfl_xor(mv, off); int op = __shfl_xor(mp, off);
        if (ov > mv || (ov == mv && op < mp)) { mv = ov; mp = op; }
      }
      tops[iter] = mv; tpos[iter] = mp;
      if ((mp & 63) == t) {
        int j = mp >> 6;
        if (j == 0) v0 = NEGINF; else if (j == 1) v1 = NEGINF;
        else if (j == 2) v2 = NEGINF; else v3 = NEGINF;
      }
    }
    if (t == 0) {
      const float kscale = 1.f/16.f;  // 1/sqrt(256)
      float mx = tops[0]*kscale, se = 0.f, ex[KK];
      #pragma unroll
      for (int k = 0; k < KK; ++k) { ex[k] = expf(tops[k]*kscale - mx); se += ex[k]; }
      float inv = 1.f / se;
      #pragma unroll
      for (int k = 0; k < KK; ++k) { w8[k] = ex[k]*inv; i8[k] = s_ix[tpos[k]]; }
    }
  }
  __syncthreads();
  size_t orow = (size_t)tok * DM;
  float4 o = *reinterpret_cast<const float4*>(xout + orow + t*4);
  #pragma unroll
  for (int k = 0; k < KK; ++k) {
    float w = w8[k];
    const float4 v4 = *reinterpret_cast<const float4*>(kV + (size_t)i8[k]*DM + t*4);
    o.x += w*v4.x; o.y += w*v4.y; o.z += w*v4.z; o.w += w*v4.w;
  }
  *reinterpret_cast<float4*>(xout + orow + t*4) = o;
}

extern "C" void kernel_launch(void* const* d_in, const int* in_sizes, int n_in,
                              void* d_out, int out_size, void* d_ws, size_t ws_size,
                              hipStream_t stream) {
  const float* x  = (const float*)d_in[0];
  const float* cn = (const float*)d_in[2];
  const float* en = (const float*)d_in[3];
  const float* kK = (const float*)d_in[4];
  const float* kV = (const float*)d_in[5];
  const float* rq = (const float*)d_in[6];
  const float* rk = (const float*)d_in[7];
  const float* rv = (const float*)d_in[8];
  const float* ro = (const float*)d_in[9];
  const float* rm = (const float*)d_in[10];
  const float* g1 = (const float*)d_in[11];
  const float* b1 = (const float*)d_in[12];
  const float* g2 = (const float*)d_in[13];
  const float* b2 = (const float*)d_in[14];
  float* out = (float*)d_out;

  char* p = (char*)d_ws;
  auto alloc = [&](size_t bytes) { char* r = p; p += (bytes + 255) & ~(size_t)255; return r; };
  unsigned short* h_h  = (unsigned short*)alloc((size_t)BS*DM*2);
  unsigned short* h_l  = (unsigned short*)alloc((size_t)BS*DM*2);
  unsigned short* h2_h = (unsigned short*)alloc((size_t)BS*DM*2);
  unsigned short* h2_l = (unsigned short*)alloc((size_t)BS*DM*2);
  unsigned short* cnT_h = (unsigned short*)alloc((size_t)64*RK*DM*2);
  unsigned short* cnT_l = (unsigned short*)alloc((size_t)64*RK*DM*2);
  float* Q    = (float*)alloc((size_t)BS*RK*4);   // Q,Kb,Vb,Qm contiguous for one memset
  float* Kb   = (float*)alloc((size_t)BS*RK*4);
  float* Vb   = (float*)alloc((size_t)BS*RK*4);
  float* Qm   = (float*)alloc((size_t)BS*RK*4);
  float* AO   = (float*)alloc((size_t)BS*RK*4);
  float* w_all= (float*)alloc((size_t)3*BS*CK*4);
  float* w_o  = (float*)alloc((size_t)BS*EK*4);
  float* w_m  = (float*)alloc((size_t)BS*CK*4);
  float* cand_s = (float*)alloc((size_t)BS*KCH*KK*4);
  int*   cand_i = (int*)  alloc((size_t)BS*KCH*KK*4);
  unsigned short* Qmb = (unsigned short*)alloc((size_t)BS*RK*2);
  unsigned short* kKb = (unsigned short*)alloc((size_t)NKN*RK*2);
  int* lists  = (int*)alloc((size_t)5*64*BS*4);   // [q,k,v,o,m]
  int* counts = (int*)alloc((size_t)5*64*4);

  int *listo = lists + 3*64*BS, *listm = lists + 4*64*BS;
  int *co = counts + 192, *cm = counts + 256;

  hipMemsetAsync(counts, 0, 5*64*4, stream);
  hipMemsetAsync(Q, 0, (size_t)BS*RK*4*4, stream);  // zeros Q, Kb, Vb, Qm

  cvt_cnT<<<dim3(32, 8, 64), 256, 0, stream>>>(cn, cnT_h, cnT_l);
  f2bf<<<NKN*RK/8/256, 256, 0, stream>>>(kK, kKb, NKN*RK/8);

  ln_router3<<<BS, 256, 0, stream>>>(x, g1, b1, h_h, h_l, rq, rk, rv, w_all, lists, counts);
  ggemm_mfma<<<dim3(64, 16, 3), 256, 0, stream>>>(h_h, h_l, cnT_h, cnT_l,
                                                  w_all, lists, counts, Q);

  attn_kernel<<<dim3(512, 32), 256, 0, stream>>>(Q, Kb, Vb, AO);

  hipMemcpyAsync(out, x, (size_t)BS*DM*4, hipMemcpyDeviceToDevice, stream);  // out = x

  router_topk<RK, EK><<<BS, 256, 0, stream>>>(AO, ro, w_o, listo, co);
  ggemm_f32<RK, DM, EK><<<dim3(64, 16, 4), 256, 0, stream>>>(AO, en, w_o, listo, co, out); // out = x1

  ln_router1<<<BS, 256, 0, stream>>>(out, g2, b2, h2_h, h2_l, rm, w_m, listm, cm);
  ggemm_mfma<<<dim3(64, 16, 1), 256, 0, stream>>>(h2_h, h2_l, cnT_h, cnT_l,
                                                  w_m, listm, cm, Qm);

  f2bf<<<BS*RK/8/256, 256, 0, stream>>>(Qm, Qmb, BS*RK/8);
  kscore_mfma<<<dim3(BS/32, KCH), 256, 0, stream>>>(Qmb, kKb, cand_s, cand_i);
  knowledge_merge<<<BS, 256, 0, stream>>>(cand_s, cand_i, kV, out);  // out = x1 + mem_out
}

// Round 10
// 1435.828 us; speedup vs baseline: 2.1589x; 1.1653x over previous
//
#include <hip/hip_runtime.h>

#define BS   2048     // B*S tokens
#define DM   1024     // D_MODEL
#define RK   256      // RANK
#define NKN  8192     // N_KNOWLEDGE
#define CK   8        // COMPRESS_TOP_K
#define EK   4        // EXPAND_TOP_K
#define KK   8        // KNOWLEDGE_K
#define KCH  32       // knowledge chunks of 256

#define NEGINF -1e30f

typedef __attribute__((ext_vector_type(8))) short short8;   // 8 bf16
typedef __attribute__((ext_vector_type(4))) float f32x4;

__device__ __forceinline__ unsigned short bf16_rtn(float v) {
  unsigned bits = __float_as_uint(v);
  return (unsigned short)((bits + 0x7fffu + ((bits >> 16) & 1u)) >> 16);
}
__device__ __forceinline__ float bf16f(unsigned short u) {
  return __uint_as_float(((unsigned)u) << 16);
}
__device__ __forceinline__ void split2(float v, unsigned short& h, unsigned short& l) {
  h = bf16_rtn(v);
  l = bf16_rtn(v - bf16f(h));
}

// ---- wave-parallel top-k over 64 scores held one-per-lane ----
template<int TOPK>
__device__ inline void wave_topk64(float bv, int lane, float* tops, int* tidx) {
  #pragma unroll
  for (int k = 0; k < TOPK; ++k) {
    float mv = bv; int mp = lane;
    #pragma unroll
    for (int off = 32; off > 0; off >>= 1) {
      float ov = __shfl_xor(mv, off); int op = __shfl_xor(mp, off);
      if (ov > mv || (ov == mv && op < mp)) { mv = ov; mp = op; }
    }
    tops[k] = mv; tidx[k] = mp;
    if (lane == mp) bv = NEGINF;
  }
}

template<int TOPK>
__device__ inline void router_commit(int token, const float* tops, const int* tidx,
    float* w_out, int* lists, int* counts) {
  float mx = tops[0], se = 0.f, ex[TOPK];
  #pragma unroll
  for (int k = 0; k < TOPK; ++k) { ex[k] = expf(tops[k] - mx); se += ex[k]; }
  float inv = 1.f / se;
  #pragma unroll
  for (int k = 0; k < TOPK; ++k) {
    w_out[token*TOPK + k] = ex[k] * inv;
    int pos = atomicAdd(&counts[tidx[k]], 1);
    lists[tidx[k]*BS + pos] = token*TOPK + k;
  }
}

// ------------- Router weight transpose: rw [64][dim4*4] -> rwT [dim4][64][4] -------------
__global__ __launch_bounds__(256) void cvt_rwT(const float* __restrict__ rw,
                                               float* __restrict__ rwT, int dim4) {
  int i = blockIdx.x*256 + threadIdx.x;     // over 64*dim4 float4s
  if (i >= 64*dim4) return;
  int n = i / dim4, jg = i % dim4;          // reads coalesced along jg
  float4 v = *reinterpret_cast<const float4*>(rw + (size_t)n*dim4*4 + jg*4);
  *reinterpret_cast<float4*>(rwT + (size_t)jg*256 + n*4) = v;
}

// ------------- Fused LN1 + QKV router (coalesced transposed weights) -------------
__global__ __launch_bounds__(256) void ln_router3(const float* __restrict__ xin,
    const float* __restrict__ g, const float* __restrict__ bb,
    unsigned short* __restrict__ hh, unsigned short* __restrict__ hl,
    const float* __restrict__ w0T, const float* __restrict__ w1T, const float* __restrict__ w2T,
    float* __restrict__ w_all, int* __restrict__ lists, int* __restrict__ counts) {
  int row = blockIdx.x, t = threadIdx.x;
  __shared__ float red[256];
  __shared__ __align__(16) float hrow[DM];
  __shared__ float part[3][4][64];
  const float4 v = *reinterpret_cast<const float4*>(xin + (size_t)row*DM + t*4);
  red[t] = v.x + v.y + v.z + v.w;
  __syncthreads();
  for (int o = 128; o > 0; o >>= 1) { if (t < o) red[t] += red[t+o]; __syncthreads(); }
  float mu = red[0] * (1.f/DM);
  __syncthreads();
  float dx = v.x-mu, dy = v.y-mu, dz = v.z-mu, dw = v.w-mu;
  red[t] = dx*dx + dy*dy + dz*dz + dw*dw;
  __syncthreads();
  for (int o = 128; o > 0; o >>= 1) { if (t < o) red[t] += red[t+o]; __syncthreads(); }
  float rs = rsqrtf(red[0]*(1.f/DM) + 1e-5f);
  float4 gv = *reinterpret_cast<const float4*>(g + t*4);
  float4 bv = *reinterpret_cast<const float4*>(bb + t*4);
  float4 o4 = make_float4(dx*rs*gv.x+bv.x, dy*rs*gv.y+bv.y, dz*rs*gv.z+bv.z, dw*rs*gv.w+bv.w);
  ushort4 uh, ul;
  split2(o4.x, uh.x, ul.x); split2(o4.y, uh.y, ul.y);
  split2(o4.z, uh.z, ul.z); split2(o4.w, uh.w, ul.w);
  *reinterpret_cast<ushort4*>(hh + (size_t)row*DM + t*4) = uh;
  *reinterpret_cast<ushort4*>(hl + (size_t)row*DM + t*4) = ul;
  *reinterpret_cast<float4*>(&hrow[t*4]) = o4;
  __syncthreads();
  // router: lane n reads rwT[jg*256 + n*4] -> coalesced; hrow broadcast from LDS
  int n = t & 63, c = t >> 6;
  const float4* b0p = reinterpret_cast<const float4*>(w0T) + (size_t)c*64*64 + n;
  const float4* b1p = reinterpret_cast<const float4*>(w1T) + (size_t)c*64*64 + n;
  const float4* b2p = reinterpret_cast<const float4*>(w2T) + (size_t)c*64*64 + n;
  float p0 = 0.f, p1 = 0.f, p2 = 0.f;
  #pragma unroll 8
  for (int jg = 0; jg < 64; ++jg) {
    float4 a  = *reinterpret_cast<const float4*>(&hrow[(c*64 + jg)*4]);
    float4 b0 = b0p[(size_t)jg*64];
    float4 b1 = b1p[(size_t)jg*64];
    float4 b2 = b2p[(size_t)jg*64];
    p0 += a.x*b0.x + a.y*b0.y + a.z*b0.z + a.w*b0.w;
    p1 += a.x*b1.x + a.y*b1.y + a.z*b1.z + a.w*b1.w;
    p2 += a.x*b2.x + a.y*b2.y + a.z*b2.z + a.w*b2.w;
  }
  part[0][c][n] = p0; part[1][c][n] = p1; part[2][c][n] = p2;
  __syncthreads();
  int wv = t >> 6, lane = t & 63;
  if (wv < 3) {
    float bvv = part[wv][0][lane] + part[wv][1][lane] + part[wv][2][lane] + part[wv][3][lane];
    float tops[CK]; int tidx[CK];
    wave_topk64<CK>(bvv, lane, tops, tidx);
    if (lane == 0)
      router_commit<CK>(row, tops, tidx, w_all + (size_t)wv*BS*CK,
                        lists + (size_t)wv*64*BS, counts + wv*64);
  }
}

// ------------- Fused LN2 + memory router (coalesced transposed weights) -------------
__global__ __launch_bounds__(256) void ln_router1(const float* __restrict__ xin,
    const float* __restrict__ g, const float* __restrict__ bb,
    unsigned short* __restrict__ hh, unsigned short* __restrict__ hl,
    const float* __restrict__ rwT,
    float* __restrict__ w_out, int* __restrict__ lists, int* __restrict__ counts) {
  int row = blockIdx.x, t = threadIdx.x;
  __shared__ float red[256];
  __shared__ __align__(16) float hrow[DM];
  __shared__ float part[4][64];
  const float4 v = *reinterpret_cast<const float4*>(xin + (size_t)row*DM + t*4);
  red[t] = v.x + v.y + v.z + v.w;
  __syncthreads();
  for (int o = 128; o > 0; o >>= 1) { if (t < o) red[t] += red[t+o]; __syncthreads(); }
  float mu = red[0] * (1.f/DM);
  __syncthreads();
  float dx = v.x-mu, dy = v.y-mu, dz = v.z-mu, dw = v.w-mu;
  red[t] = dx*dx + dy*dy + dz*dz + dw*dw;
  __syncthreads();
  for (int o = 128; o > 0; o >>= 1) { if (t < o) red[t] += red[t+o]; __syncthreads(); }
  float rs = rsqrtf(red[0]*(1.f/DM) + 1e-5f);
  float4 gv = *reinterpret_cast<const float4*>(g + t*4);
  float4 bv = *reinterpret_cast<const float4*>(bb + t*4);
  float4 o4 = make_float4(dx*rs*gv.x+bv.x, dy*rs*gv.y+bv.y, dz*rs*gv.z+bv.z, dw*rs*gv.w+bv.w);
  ushort4 uh, ul;
  split2(o4.x, uh.x, ul.x); split2(o4.y, uh.y, ul.y);
  split2(o4.z, uh.z, ul.z); split2(o4.w, uh.w, ul.w);
  *reinterpret_cast<ushort4*>(hh + (size_t)row*DM + t*4) = uh;
  *reinterpret_cast<ushort4*>(hl + (size_t)row*DM + t*4) = ul;
  *reinterpret_cast<float4*>(&hrow[t*4]) = o4;
  __syncthreads();
  int n = t & 63, c = t >> 6;
  const float4* bp = reinterpret_cast<const float4*>(rwT) + (size_t)c*64*64 + n;
  float p = 0.f;
  #pragma unroll 8
  for (int jg = 0; jg < 64; ++jg) {
    float4 a = *reinterpret_cast<const float4*>(&hrow[(c*64 + jg)*4]);
    float4 b = bp[(size_t)jg*64];
    p += a.x*b.x + a.y*b.y + a.z*b.z + a.w*b.w;
  }
  part[c][n] = p;
  __syncthreads();
  if (t < 64) {
    float bvv = part[0][t] + part[1][t] + part[2][t] + part[3][t];
    float tops[CK]; int tidx[CK];
    wave_topk64<CK>(bvv, t, tops, tidx);
    if (t == 0) router_commit<CK>(row, tops, tidx, w_out, lists, counts);
  }
}

// ------------- Expand router on AO (coalesced transposed weights) -------------
template<int DIM, int TOPK>
__global__ __launch_bounds__(256) void router_topkT(const float* __restrict__ xin,
    const float* __restrict__ rwT, float* __restrict__ w_out,
    int* __restrict__ lists, int* __restrict__ counts) {
  int token = blockIdx.x, t = threadIdx.x;
  __shared__ __align__(16) float xrow[DIM];
  __shared__ float part[4][64];
  for (int i = t; i < DIM/4; i += 256)
    *reinterpret_cast<float4*>(&xrow[i*4]) =
        *reinterpret_cast<const float4*>(xin + (size_t)token*DIM + i*4);
  __syncthreads();
  int n = t & 63, c = t >> 6;
  const int JG = DIM / 16;   // j-groups per chunk
  const float4* bp = reinterpret_cast<const float4*>(rwT) + (size_t)c*JG*64 + n;
  float p = 0.f;
  #pragma unroll 8
  for (int jg = 0; jg < JG; ++jg) {
    float4 a = *reinterpret_cast<const float4*>(&xrow[(c*JG + jg)*4]);
    float4 b = bp[(size_t)jg*64];
    p += a.x*b.x + a.y*b.y + a.z*b.z + a.w*b.w;
  }
  part[c][n] = p;
  __syncthreads();
  if (t < 64) {
    float bv = part[0][t] + part[1][t] + part[2][t] + part[3][t];
    float tops[TOPK]; int tidx[TOPK];
    wave_topk64<TOPK>(bv, t, tops, tidx);
    if (t == 0) router_commit<TOPK>(token, tops, tidx, w_out, lists, counts);
  }
}

// ------------- cn [e][k][c] f32 -> cnT_hi/lo [e][c][k] bf16 (transpose+split) -------------
__global__ __launch_bounds__(256) void cvt_cnT(const float* __restrict__ cn,
    unsigned short* __restrict__ th, unsigned short* __restrict__ tl) {
  __shared__ float tile[32][33];
  int kb = blockIdx.x*32, cb = blockIdx.y*32, e = blockIdx.z;
  int tx = threadIdx.x & 31, ty = threadIdx.x >> 5;
  const size_t ebase = (size_t)e * DM * RK;
  for (int r = ty; r < 32; r += 8)
    tile[r][tx] = cn[ebase + (size_t)(kb + r)*RK + cb + tx];
  __syncthreads();
  for (int r = ty; r < 32; r += 8) {
    float v = tile[tx][r];
    unsigned short h, l; split2(v, h, l);
    size_t o = (size_t)e*RK*DM + (size_t)(cb + r)*DM + kb + tx;
    th[o] = h; tl[o] = l;
  }
}

// ------------- Grouped compress GEMM via split-bf16 MFMA (fp32-accurate) -------------
__global__ __launch_bounds__(256) void ggemm_mfma(
    const unsigned short* __restrict__ xh, const unsigned short* __restrict__ xl,
    const unsigned short* __restrict__ WTh, const unsigned short* __restrict__ WTl,
    const float* __restrict__ w_all, const int* __restrict__ lists,
    const int* __restrict__ counts, float* __restrict__ out) {
  int e = blockIdx.x, which = blockIdx.z;
  int cnt = counts[which*64 + e];
  int base = blockIdx.y * 64;
  if (base >= cnt) return;
  const int* list_e = lists + ((size_t)which*64 + e)*BS;
  const float* wvp = w_all + (size_t)which*BS*CK;
  int t = threadIdx.x, w = t >> 6, l = t & 63, lr = l & 15, lg = l >> 4;
  __shared__ int   toks[64];
  __shared__ float wts[64];
  if (t < 64) {
    int idx = base + t;
    if (idx < cnt) { int e2 = list_e[idx]; toks[t] = e2 / CK; wts[t] = wvp[e2]; }
    else           { toks[t] = -1; wts[t] = 0.f; }
  }
  __syncthreads();
  f32x4 acc[4][4];
  #pragma unroll
  for (int mi = 0; mi < 4; ++mi)
    #pragma unroll
    for (int ni = 0; ni < 4; ++ni) acc[mi][ni] = (f32x4)0.f;
  const unsigned short* Ahb = WTh + ((size_t)e*RK + w*64 + lr)*DM + lg*8;
  const unsigned short* Alb = WTl + ((size_t)e*RK + w*64 + lr)*DM + lg*8;
  int tokn[4]; float wtn[4];
  const unsigned short *Bh[4], *Bl[4];
  #pragma unroll
  for (int ni = 0; ni < 4; ++ni) {
    tokn[ni] = toks[ni*16 + lr];
    wtn[ni]  = wts[ni*16 + lr];
    int tk = tokn[ni] >= 0 ? tokn[ni] : 0;
    Bh[ni] = xh + (size_t)tk*DM + lg*8;
    Bl[ni] = xl + (size_t)tk*DM + lg*8;
  }
  for (int k0 = 0; k0 < DM; k0 += 32) {
    short8 ah[4], al[4], bh[4], bl[4];
    #pragma unroll
    for (int mi = 0; mi < 4; ++mi) {
      ah[mi] = *reinterpret_cast<const short8*>(Ahb + (size_t)mi*16*DM + k0);
      al[mi] = *reinterpret_cast<const short8*>(Alb + (size_t)mi*16*DM + k0);
    }
    #pragma unroll
    for (int ni = 0; ni < 4; ++ni) {
      bh[ni] = *reinterpret_cast<const short8*>(Bh[ni] + k0);
      bl[ni] = *reinterpret_cast<const short8*>(Bl[ni] + k0);
    }
    #pragma unroll
    for (int mi = 0; mi < 4; ++mi)
      #pragma unroll
      for (int ni = 0; ni < 4; ++ni) {
        acc[mi][ni] = __builtin_amdgcn_mfma_f32_16x16x32_bf16(ah[mi], bh[ni], acc[mi][ni], 0, 0, 0);
        acc[mi][ni] = __builtin_amdgcn_mfma_f32_16x16x32_bf16(ah[mi], bl[ni], acc[mi][ni], 0, 0, 0);
        acc[mi][ni] = __builtin_amdgcn_mfma_f32_16x16x32_bf16(al[mi], bh[ni], acc[mi][ni], 0, 0, 0);
      }
  }
  #pragma unroll
  for (int ni = 0; ni < 4; ++ni) {
    if (tokn[ni] < 0) continue;
    float wt = wtn[ni];
    float* orow = out + ((size_t)which*BS + tokn[ni])*RK;
    #pragma unroll
    for (int mi = 0; mi < 4; ++mi) {
      int col = w*64 + mi*16 + lg*4;
      #pragma unroll
      for (int r = 0; r < 4; ++r)
        atomicAdd(&orow[col + r], wt * acc[mi][ni][r]);
    }
  }
}

// ------------- Expand grouped SGEMM (fp32) -------------
template<int KDIM, int NCOLT, int TK>
__global__ __launch_bounds__(256) void ggemm_f32(const float* __restrict__ xin,
    const float* __restrict__ neurons, const float* __restrict__ w_all,
    const int* __restrict__ lists, const int* __restrict__ counts,
    float* __restrict__ out) {
  constexpr int COLCH = NCOLT / 256;
  int e = blockIdx.x;
  int which = blockIdx.z / COLCH, cc = blockIdx.z % COLCH;
  int cnt = counts[which*64 + e];
  int base = blockIdx.y * 64;
  if (base >= cnt) return;
  const int* list_e = lists + ((size_t)which*64 + e)*BS;
  const float* wvp = w_all + (size_t)which*BS*TK;
  int t = threadIdx.x;
  __shared__ __align__(16) float Bs[16][256];
  __shared__ __align__(16) float At[16][64];
  __shared__ int   toks[64];
  __shared__ float wts[64];
  if (t < 64) {
    int idx = base + t;
    if (idx < cnt) { int e2 = list_e[idx]; toks[t] = e2 / TK; wts[t] = wvp[e2]; }
    else           { toks[t] = -1; wts[t] = 0.f; }
  }
  __syncthreads();
  float acc[8][8];
  #pragma unroll
  for (int i = 0; i < 8; ++i)
    #pragma unroll
    for (int j = 0; j < 8; ++j) acc[i][j] = 0.f;
  int tr = t >> 5, tc = t & 31;
  const float* W = neurons + (size_t)e*KDIM*NCOLT + cc*256;
  int ar = t & 63, akc = (t >> 6) * 4;
  int tokA = toks[ar];
  const float* Arow = xin + (size_t)(tokA >= 0 ? tokA : 0)*KDIM + akc;

  for (int k0 = 0; k0 < KDIM; k0 += 16) {
    float4 b0r, b1r, b2r, b3r;
    {
      int f0 = t*4;
      b0r = *reinterpret_cast<const float4*>(W + (size_t)(k0 + (f0>>8))*NCOLT + (f0&255));
      int f1 = 1024 + t*4;
      b1r = *reinterpret_cast<const float4*>(W + (size_t)(k0 + (f1>>8))*NCOLT + (f1&255));
      int f2 = 2048 + t*4;
      b2r = *reinterpret_cast<const float4*>(W + (size_t)(k0 + (f2>>8))*NCOLT + (f2&255));
      int f3 = 3072 + t*4;
      b3r = *reinterpret_cast<const float4*>(W + (size_t)(k0 + (f3>>8))*NCOLT + (f3&255));
    }
    float4 av = *reinterpret_cast<const float4*>(Arow + k0);
    if (tokA < 0) av = make_float4(0.f, 0.f, 0.f, 0.f);
    __syncthreads();
    {
      int f0 = t*4;
      *reinterpret_cast<float4*>(&Bs[0][0] + f0)        = b0r;
      *reinterpret_cast<float4*>(&Bs[0][0] + f0 + 1024) = b1r;
      *reinterpret_cast<float4*>(&Bs[0][0] + f0 + 2048) = b2r;
      *reinterpret_cast<float4*>(&Bs[0][0] + f0 + 3072) = b3r;
      At[akc+0][ar] = av.x; At[akc+1][ar] = av.y;
      At[akc+2][ar] = av.z; At[akc+3][ar] = av.w;
    }
    __syncthreads();
    #pragma unroll
    for (int kk = 0; kk < 16; ++kk) {
      float4 a0 = *reinterpret_cast<const float4*>(&At[kk][tr*8]);
      float4 a1 = *reinterpret_cast<const float4*>(&At[kk][tr*8 + 4]);
      float4 p0 = *reinterpret_cast<const float4*>(&Bs[kk][tc*4]);
      float4 p1 = *reinterpret_cast<const float4*>(&Bs[kk][128 + tc*4]);
      float a[8] = {a0.x,a0.y,a0.z,a0.w,a1.x,a1.y,a1.z,a1.w};
      float b[8] = {p0.x,p0.y,p0.z,p0.w,p1.x,p1.y,p1.z,p1.w};
      #pragma unroll
      for (int i = 0; i < 8; ++i)
        #pragma unroll
        for (int j = 0; j < 8; ++j)
          acc[i][j] = fmaf(a[i], b[j], acc[i][j]);
    }
  }
  #pragma unroll
  for (int i = 0; i < 8; ++i) {
    int r = tr*8 + i;
    int tok = toks[r];
    if (tok < 0) continue;
    float wt = wts[r];
    float* orow = out + ((size_t)which*BS + tok)*NCOLT + cc*256;
    #pragma unroll
    for (int j = 0; j < 4; ++j) {
      atomicAdd(&orow[tc*4 + j],       wt * acc[i][j]);
      atomicAdd(&orow[128 + tc*4 + j], wt * acc[i][j+4]);
    }
  }
}

// ------------- Attention: one block per (q, head*batch) -------------
__global__ __launch_bounds__(256) void attn_kernel(const float* __restrict__ Q,
    const float* __restrict__ K, const float* __restrict__ V, float* __restrict__ AO) {
  int qs = blockIdx.x;
  int hb = blockIdx.y; int h = hb & 7, b = hb >> 3;
  int t = threadIdx.x;
  __shared__ float qv[32];
  __shared__ float sc[512];
  __shared__ float red[256];
  const size_t baseQ = ((size_t)(b*512 + qs))*RK + h*32;
  if (t < 32) qv[t] = Q[baseQ + t];
  __syncthreads();
  int nk = qs + 1;
  const float scale = 0.17677669529663687f;  // 1/sqrt(32)
  for (int k = t; k < nk; k += 256) {
    const float* kr = K + ((size_t)(b*512 + k))*RK + h*32;
    float s = 0.f;
    #pragma unroll
    for (int d = 0; d < 32; d += 4) {
      float4 kv = *reinterpret_cast<const float4*>(kr + d);
      s += kv.x*qv[d] + kv.y*qv[d+1] + kv.z*qv[d+2] + kv.w*qv[d+3];
    }
    sc[k] = s * scale;
  }
  __syncthreads();
  float m = NEGINF;
  for (int k = t; k < nk; k += 256) m = fmaxf(m, sc[k]);
  red[t] = m; __syncthreads();
  for (int o = 128; o > 0; o >>= 1) { if (t < o) red[t] = fmaxf(red[t], red[t+o]); __syncthreads(); }
  m = red[0];
  __syncthreads();
  float sloc = 0.f;
  for (int k = t; k < nk; k += 256) { float pp = expf(sc[k] - m); sc[k] = pp; sloc += pp; }
  red[t] = sloc; __syncthreads();
  for (int o = 128; o > 0; o >>= 1) { if (t < o) red[t] += red[t+o]; __syncthreads(); }
  float inv = 1.f / red[0];
  __syncthreads();
  int d = t & 31, c = t >> 5;
  float pa = 0.f;
  for (int k = c; k < nk; k += 8)
    pa += sc[k] * V[((size_t)(b*512 + k))*RK + h*32 + d];
  red[c*32 + d] = pa; __syncthreads();
  if (t < 32) {
    float o = 0.f;
    #pragma unroll
    for (int c2 = 0; c2 < 8; ++c2) o += red[c2*32 + t];
    AO[baseQ + t] = o * inv;
  }
}

// ------------- f32 -> bf16 (RTN), 8 elems/thread -------------
__global__ __launch_bounds__(256) void f2bf(const float* __restrict__ in,
                                            unsigned short* __restrict__ out, int n8) {
  int i = blockIdx.x*256 + threadIdx.x;
  if (i >= n8) return;
  float4 a = reinterpret_cast<const float4*>(in)[2*i];
  float4 b = reinterpret_cast<const float4*>(in)[2*i + 1];
  float v[8] = {a.x,a.y,a.z,a.w,b.x,b.y,b.z,b.w};
  unsigned u[8];
  #pragma unroll
  for (int j = 0; j < 8; ++j) {
    unsigned bits = __float_as_uint(v[j]);
    u[j] = (bits + 0x7fffu + ((bits >> 16) & 1u)) >> 16;
  }
  uint4 o;
  o.x = u[0] | (u[1] << 16); o.y = u[2] | (u[3] << 16);
  o.z = u[4] | (u[5] << 16); o.w = u[6] | (u[7] << 16);
  *reinterpret_cast<uint4*>(out + 8*i) = o;
}

// ------------- Knowledge scores via bf16 MFMA + per-chunk top-8 -------------
__global__ __launch_bounds__(256) void kscore_mfma(const unsigned short* __restrict__ Qmb,
    const unsigned short* __restrict__ kKb, float* __restrict__ cand_s, int* __restrict__ cand_i) {
  int tile = blockIdx.x, chunk = blockIdx.y;
  int t = threadIdx.x, w = t >> 6, l = t & 63;
  int lr = l & 15, lg = l >> 4;
  __shared__ float sc[32][265];
  f32x4 acc[4][2];
  #pragma unroll
  for (int mi = 0; mi < 4; ++mi)
    #pragma unroll
    for (int ti = 0; ti < 2; ++ti) acc[mi][ti] = (f32x4)0.f;
  const unsigned short* Abase = kKb + ((size_t)(chunk*256 + w*64 + lr))*RK + lg*8;
  const unsigned short* Bbase = Qmb + ((size_t)(tile*32 + lr))*RK + lg*8;
  #pragma unroll
  for (int k0 = 0; k0 < RK; k0 += 32) {
    short8 af[4], bf[2];
    #pragma unroll
    for (int mi = 0; mi < 4; ++mi)
      af[mi] = *reinterpret_cast<const short8*>(Abase + (size_t)mi*16*RK + k0);
    #pragma unroll
    for (int ti = 0; ti < 2; ++ti)
      bf[ti] = *reinterpret_cast<const short8*>(Bbase + (size_t)ti*16*RK + k0);
    #pragma unroll
    for (int mi = 0; mi < 4; ++mi)
      #pragma unroll
      for (int ti = 0; ti < 2; ++ti)
        acc[mi][ti] = __builtin_amdgcn_mfma_f32_16x16x32_bf16(af[mi], bf[ti], acc[mi][ti], 0, 0, 0);
  }
  #pragma unroll
  for (int mi = 0; mi < 4; ++mi)
    #pragma unroll
    for (int ti = 0; ti < 2; ++ti)
      #pragma unroll
      for (int r = 0; r < 4; ++r)
        sc[ti*16 + lr][w*64 + mi*16 + lg*4 + r] = acc[mi][ti][r];
  __syncthreads();
  for (int s = 0; s < 8; ++s) {
    int tok = w*8 + s;
    float v0 = sc[tok][l], v1 = sc[tok][l+64], v2 = sc[tok][l+128], v3 = sc[tok][l+192];
    size_t cbase = ((size_t)(tile*32 + tok)*KCH + chunk)*KK;
    #pragma unroll
    for (int iter = 0; iter < KK; ++iter) {
      float mv = v0; int mp = l;
      if (v1 > mv) { mv = v1; mp = l+64; }
      if (v2 > mv) { mv = v2; mp = l+128; }
      if (v3 > mv) { mv = v3; mp = l+192; }
      #pragma unroll
      for (int off = 32; off > 0; off >>= 1) {
        float ov = __shfl_xor(mv, off); int op = __shfl_xor(mp, off);
        if (ov > mv || (ov == mv && op < mp)) { mv = ov; mp = op; }
      }
      if ((mp & 63) == l) {
        int j = mp >> 6;
        if (j == 0) v0 = NEGINF; else if (j == 1) v1 = NEGINF;
        else if (j == 2) v2 = NEGINF; else v3 = NEGINF;
      }
      if (l == 0) { cand_s[cbase + iter] = mv; cand_i[cbase + iter] = chunk*256 + mp; }
    }
  }
}

// ------------- Knowledge merge: 256 candidates -> top-8, softmax, V gather -------------
__global__ __launch_bounds__(256) void knowledge_merge(const float* __restrict__ cand_s,
    const int* __restrict__ cand_i, const float* __restrict__ kV, float* __restrict__ xout) {
  int tok = blockIdx.x, t = threadIdx.x;
  __shared__ float s_sc[256];
  __shared__ int   s_ix[256];
  __shared__ float w8[KK];
  __shared__ int   i8[KK];
  s_sc[t] = cand_s[(size_t)tok*256 + t];
  s_ix[t] = cand_i[(size_t)tok*256 + t];
  __syncthreads();
  if (t < 64) {
    float v0 = s_sc[t], v1 = s_sc[t+64], v2 = s_sc[t+128], v3 = s_sc[t+192];
    float tops[KK]; int tpos[KK];
    #pragma unroll
    for (int iter = 0; iter < KK; ++iter) {
      float mv = v0; int mp = t;
      if (v1 > mv) { mv = v1; mp = t+64; }
      if (v2 > mv) { mv = v2; mp = t+128; }
      if (v3 > mv) { mv = v3; mp = t+192; }
      #pragma unroll
      for (int off = 32; off > 0; off >>= 1) {
        float ov = __shfl_xor(mv, off); int op = __shfl_xor(mp, off);
        if (ov > mv || (ov == mv && op < mp)) { mv = ov; mp = op; }
      }
      tops[iter] = mv; tpos[iter] = mp;
      if ((mp & 63) == t) {
        int j = mp >> 6;
        if (j == 0) v0 = NEGINF; else if (j == 1) v1 = NEGINF;
        else if (j == 2) v2 = NEGINF; else v3 = NEGINF;
      }
    }
    if (t == 0) {
      const float kscale = 1.f/16.f;  // 1/sqrt(256)
      float mx = tops[0]*kscale, se = 0.f, ex[KK];
      #pragma unroll
      for (int k = 0; k < KK; ++k) { ex[k] = expf(tops[k]*kscale - mx); se += ex[k]; }
      float inv = 1.f / se;
      #pragma unroll
      for (int k = 0; k < KK; ++k) { w8[k] = ex[k]*inv; i8[k] = s_ix[tpos[k]]; }
    }
  }
  __syncthreads();
  size_t orow = (size_t)tok * DM;
  float4 o = *reinterpret_cast<const float4*>(xout + orow + t*4);
  #pragma unroll
  for (int k = 0; k < KK; ++k) {
    float w = w8[k];
    const float4 v4 = *reinterpret_cast<const float4*>(kV + (size_t)i8[k]*DM + t*4);
    o.x += w*v4.x; o.y += w*v4.y; o.z += w*v4.z; o.w += w*v4.w;
  }
  *reinterpret_cast<float4*>(xout + orow + t*4) = o;
}

extern "C" void kernel_launch(void* const* d_in, const int* in_sizes, int n_in,
                              void* d_out, int out_size, void* d_ws, size_t ws_size,
                              hipStream_t stream) {
  const float* x  = (const float*)d_in[0];
  const float* cn = (const float*)d_in[2];
  const float* en = (const float*)d_in[3];
  const float* kK = (const float*)d_in[4];
  const float* kV = (const float*)d_in[5];
  const float* rq = (const float*)d_in[6];
  const float* rk = (const float*)d_in[7];
  const float* rv = (const float*)d_in[8];
  const float* ro = (const float*)d_in[9];
  const float* rm = (const float*)d_in[10];
  const float* g1 = (const float*)d_in[11];
  const float* b1 = (const float*)d_in[12];
  const float* g2 = (const float*)d_in[13];
  const float* b2 = (const float*)d_in[14];
  float* out = (float*)d_out;

  char* p = (char*)d_ws;
  auto alloc = [&](size_t bytes) { char* r = p; p += (bytes + 255) & ~(size_t)255; return r; };
  unsigned short* h_h  = (unsigned short*)alloc((size_t)BS*DM*2);
  unsigned short* h_l  = (unsigned short*)alloc((size_t)BS*DM*2);
  unsigned short* h2_h = (unsigned short*)alloc((size_t)BS*DM*2);
  unsigned short* h2_l = (unsigned short*)alloc((size_t)BS*DM*2);
  unsigned short* cnT_h = (unsigned short*)alloc((size_t)64*RK*DM*2);
  unsigned short* cnT_l = (unsigned short*)alloc((size_t)64*RK*DM*2);
  float* rqT  = (float*)alloc((size_t)64*DM*4);
  float* rkT  = (float*)alloc((size_t)64*DM*4);
  float* rvT  = (float*)alloc((size_t)64*DM*4);
  float* rmT  = (float*)alloc((size_t)64*DM*4);
  float* roT  = (float*)alloc((size_t)64*RK*4);
  float* Q    = (float*)alloc((size_t)BS*RK*4);   // Q,Kb,Vb,Qm contiguous for one memset
  float* Kb   = (float*)alloc((size_t)BS*RK*4);
  float* Vb   = (float*)alloc((size_t)BS*RK*4);
  float* Qm   = (float*)alloc((size_t)BS*RK*4);
  float* AO   = (float*)alloc((size_t)BS*RK*4);
  float* w_all= (float*)alloc((size_t)3*BS*CK*4);
  float* w_o  = (float*)alloc((size_t)BS*EK*4);
  float* w_m  = (float*)alloc((size_t)BS*CK*4);
  float* cand_s = (float*)alloc((size_t)BS*KCH*KK*4);
  int*   cand_i = (int*)  alloc((size_t)BS*KCH*KK*4);
  unsigned short* Qmb = (unsigned short*)alloc((size_t)BS*RK*2);
  unsigned short* kKb = (unsigned short*)alloc((size_t)NKN*RK*2);
  int* lists  = (int*)alloc((size_t)5*64*BS*4);   // [q,k,v,o,m]
  int* counts = (int*)alloc((size_t)5*64*4);

  int *listo = lists + 3*64*BS, *listm = lists + 4*64*BS;
  int *co = counts + 192, *cm = counts + 256;

  hipMemsetAsync(counts, 0, 5*64*4, stream);
  hipMemsetAsync(Q, 0, (size_t)BS*RK*4*4, stream);  // zeros Q, Kb, Vb, Qm

  cvt_rwT<<<64, 256, 0, stream>>>(rq, rqT, DM/4);
  cvt_rwT<<<64, 256, 0, stream>>>(rk, rkT, DM/4);
  cvt_rwT<<<64, 256, 0, stream>>>(rv, rvT, DM/4);
  cvt_rwT<<<64, 256, 0, stream>>>(rm, rmT, DM/4);
  cvt_rwT<<<16, 256, 0, stream>>>(ro, roT, RK/4);
  cvt_cnT<<<dim3(32, 8, 64), 256, 0, stream>>>(cn, cnT_h, cnT_l);
  f2bf<<<NKN*RK/8/256, 256, 0, stream>>>(kK, kKb, NKN*RK/8);

  ln_router3<<<BS, 256, 0, stream>>>(x, g1, b1, h_h, h_l, rqT, rkT, rvT, w_all, lists, counts);
  ggemm_mfma<<<dim3(64, 16, 3), 256, 0, stream>>>(h_h, h_l, cnT_h, cnT_l,
                                                  w_all, lists, counts, Q);

  attn_kernel<<<dim3(512, 32), 256, 0, stream>>>(Q, Kb, Vb, AO);

  hipMemcpyAsync(out, x, (size_t)BS*DM*4, hipMemcpyDeviceToDevice, stream);  // out = x

  router_topkT<RK, EK><<<BS, 256, 0, stream>>>(AO, roT, w_o, listo, co);
  ggemm_f32<RK, DM, EK><<<dim3(64, 16, 4), 256, 0, stream>>>(AO, en, w_o, listo, co, out); // out = x1

  ln_router1<<<BS, 256, 0, stream>>>(out, g2, b2, h2_h, h2_l, rmT, w_m, listm, cm);
  ggemm_mfma<<<dim3(64, 16, 1), 256, 0, stream>>>(h2_h, h2_l, cnT_h, cnT_l,
                                                  w_m, listm, cm, Qm);

  f2bf<<<BS*RK/8/256, 256, 0, stream>>>(Qm, Qmb, BS*RK/8);
  kscore_mfma<<<dim3(BS/32, KCH), 256, 0, stream>>>(Qmb, kKb, cand_s, cand_i);
  knowledge_merge<<<BS, 256, 0, stream>>>(cand_s, cand_i, kV, out);  // out = x1 + mem_out
}